// Round 11
// baseline (690.133 us; speedup 1.0000x reference)
//
#include <hip/hip_runtime.h>
#include <hip/hip_bf16.h>

#define NN 20000
#define EE 400000
#define RSBN 0.9999950000374997f   // 1/sqrt(1+1e-5)

typedef __attribute__((ext_vector_type(8))) short short8;
typedef __attribute__((ext_vector_type(8))) unsigned short ushort8;
typedef __attribute__((ext_vector_type(4))) short bf4;
typedef __attribute__((ext_vector_type(4))) float floatx4;

__device__ __forceinline__ short f2bf(float f) {
  union { float f; unsigned u; } v; v.f = f;
  unsigned r = v.u + 0x7fffu + ((v.u >> 16) & 1u);   // RNE
  return (short)(r >> 16);
}
__device__ __forceinline__ unsigned f2bf2(float x, float y) {   // packed cvt
  union { __hip_bfloat162 h; unsigned u; } v;
  v.h = __float22bfloat162_rn(make_float2(x, y));
  return v.u;
}
__device__ __forceinline__ float bf2f(unsigned short u) {
  union { unsigned u; float f; } v; v.u = ((unsigned)u) << 16;
  return v.f;
}
__device__ __forceinline__ void gl_lds16(const void* g, void* l) {
  __builtin_amdgcn_global_load_lds(
      (const __attribute__((address_space(1))) unsigned*)g,
      (__attribute__((address_space(3))) unsigned*)l, 16, 0, 0);
}

__device__ __forceinline__ floatx4 mfma16(bf4 a, bf4 b, floatx4 c) {
#if __has_builtin(__builtin_amdgcn_mfma_f32_16x16x16bf16_1k)
  return __builtin_amdgcn_mfma_f32_16x16x16bf16_1k(a, b, c, 0, 0, 0);
#else
  floatx4 d;
  asm volatile("v_mfma_f32_16x16x16_bf16 %0, %1, %2, %3"
               : "=&v"(d) : "v"(a), "v"(b), "v"(c));
  return d;
#endif
}

// lane^1 exchange via DPP quad_perm(1,0,3,2): full-rate VALU, no DS-pipe traffic
__device__ __forceinline__ float dpp_xor1(float x) {
  union { float f; int i; } a, b;
  a.f = x;
  b.i = __builtin_amdgcn_update_dpp(0, a.i, 0xB1, 0xF, 0xF, false);
  return b.f;
}

// bijective XCD-aware remap of a 1D block index (m204 formula)
__device__ __forceinline__ int xcd_swizzle(int bid, int nwg) {
  int q = nwg >> 3, r = nwg & 7;
  int x = bid & 7, o = bid >> 3;
  return (x < r ? x * (q + 1) : r * (q + 1) + (x - r) * q) + o;
}

// ---------------- edge-parser weights -> fragment-layout bf16 + folded consts ----------------
__global__ __launch_bounds__(256) void ewconv_kernel(
    const float* __restrict__ w1, const float* __restrict__ w2,
    const float* __restrict__ g1, const float* __restrict__ be1,
    const float* __restrict__ b1, const float* __restrict__ b2,
    unsigned short* __restrict__ ewf)
{
  int tid = threadIdx.x;
#pragma unroll
  for (int i = 0; i < 16; i++) {
    int idx = i * 256 + tid;
    int k = idx >> 7, n = idx & 127;
    int pos = ((n >> 4) * 64 + (k >> 3) * 16 + (n & 15)) * 8 + (k & 7);
    ewf[pos] = f2bf(w1[idx]);
  }
#pragma unroll
  for (int i = 0; i < 64; i++) {
    int idx = i * 256 + tid;
    int k = idx >> 7, n = idx & 127;
    int u = k >> 4, q = (k >> 2) & 3, j = k & 3;
    int t = n >> 4, l = n & 15;
    int pos = (((u * 8 + t) * 4 + q) * 16 + l) * 4 + j;
    ewf[4096 + pos] = f2bf(w2[idx] * g1[k] * RSBN);   // BN scale folded
  }
  float* fb = (float*)(ewf + 20480);
  if (tid < 128) {
    fb[tid] = b1[tid];
    float acc = b2[tid];
    for (int k = 0; k < 128; k++) acc += be1[k] * w2[k * 128 + tid] * g1[k] * RSBN;
    fb[128 + tid] = acc;
  }
}

// ---------------- edge parser + edge weight (swapped MFMA, 2 tiles/wave) ----------------
// 2-tile version (round 7, counter-verified ~73.5 us). launch_bounds(512,4) = 128 VGPR
// cap (round-2 spill lesson: past the cap, accumulators spill -> 25x scratch traffic).
__global__ __launch_bounds__(512, 4) void edge_kernel(
    const float* __restrict__ xin, const int* __restrict__ eidx,
    const unsigned short* __restrict__ ewf,
    float* __restrict__ ew_out,
    float* __restrict__ deg, int* __restrict__ cnt)
{
  __shared__ short wbuf[20992];

  int tid = threadIdx.x;
  int lane = tid & 63;
  int wv = tid >> 6;
  int l15 = lane & 15;
  int quad = lane >> 4;

#pragma unroll
  for (int i = 0; i < 5; i++)
    gl_lds16(ewf + (i * 512 + tid) * 8, &wbuf[(i * 512 + tid) * 8]);
  if (tid < 64)
    gl_lds16(ewf + (2560 + tid) * 8, &wbuf[(2560 + tid) * 8]);

  const short* w1f = wbuf;
  const short* w2f = wbuf + 4096;

  int rowA = blockIdx.x * 256 + wv * 16;
  int rowB = rowA + 128;

  short8 afA, afB;
  {
    const float* xpA = xin + (size_t)(rowA + l15) * 32 + quad * 8;
    const float* xpB = xin + (size_t)(rowB + l15) * 32 + quad * 8;
    float4 a0 = *(const float4*)xpA;
    float4 a1 = *(const float4*)(xpA + 4);
    float4 b0 = *(const float4*)xpB;
    float4 b1v = *(const float4*)(xpB + 4);
    union { short8 s; unsigned u[4]; } a, b;
    a.u[0] = f2bf2(a0.x, a0.y); a.u[1] = f2bf2(a0.z, a0.w);
    a.u[2] = f2bf2(a1.x, a1.y); a.u[3] = f2bf2(a1.z, a1.w);
    b.u[0] = f2bf2(b0.x, b0.y); b.u[1] = f2bf2(b0.z, b0.w);
    b.u[2] = f2bf2(b1v.x, b1v.y); b.u[3] = f2bf2(b1v.z, b1v.w);
    afA = a.s; afB = b.s;
  }

  __syncthreads();

  const float* fb = (const float*)(wbuf + 20480);

  floatx4 acc1A[8], acc1B[8];
#pragma unroll
  for (int t = 0; t < 8; t++) {
    floatx4 z = *(const floatx4*)&fb[t * 16 + quad * 4];   // b1 rows (tile-independent)
    short8 w1v = *(const short8*)&w1f[(t * 64 + lane) * 8];
    acc1A[t] = __builtin_amdgcn_mfma_f32_16x16x32_bf16(w1v, afA, z, 0, 0, 0);
    acc1B[t] = __builtin_amdgcn_mfma_f32_16x16x32_bf16(w1v, afB, z, 0, 0, 0);
  }

  bf4 pbA[8], pbB[8];
#pragma unroll
  for (int u = 0; u < 8; u++) {
    union { bf4 s; unsigned w[2]; } oa, ob;
    oa.w[0] = f2bf2(fmaxf(acc1A[u][0], 0.f), fmaxf(acc1A[u][1], 0.f));
    oa.w[1] = f2bf2(fmaxf(acc1A[u][2], 0.f), fmaxf(acc1A[u][3], 0.f));
    ob.w[0] = f2bf2(fmaxf(acc1B[u][0], 0.f), fmaxf(acc1B[u][1], 0.f));
    ob.w[1] = f2bf2(fmaxf(acc1B[u][2], 0.f), fmaxf(acc1B[u][3], 0.f));
    pbA[u] = oa.s; pbB[u] = ob.s;
  }

  floatx4 acc2A[8], acc2B[8];
#pragma unroll
  for (int t = 0; t < 8; t++) {
    floatx4 z2 = *(const floatx4*)&fb[128 + t * 16 + quad * 4];   // folded b2
    acc2A[t] = z2; acc2B[t] = z2;
  }
#pragma unroll
  for (int u = 0; u < 8; u++)
#pragma unroll
    for (int t = 0; t < 8; t++) {
      bf4 a4 = *(const bf4*)&w2f[((u * 8 + t) * 64 + lane) * 4];
      acc2A[t] = mfma16(a4, pbA[u], acc2A[t]);
      acc2B[t] = mfma16(a4, pbB[u], acc2B[t]);
    }

#pragma unroll
  for (int tile = 0; tile < 2; tile++) {
    floatx4* acc2 = tile ? acc2B : acc2A;
    int rowbase = tile ? rowB : rowA;
    float qq = 0.f, pp = 0.f;
#pragma unroll
    for (int t = 0; t < 8; t++)
#pragma unroll
      for (int r = 0; r < 4; r++) {
        float h = acc2[t][r];
        float hp = dpp_xor1(h);
        qq += h * h;
        pp += h * hp;
      }
    qq += __shfl_xor(qq, 16, 64);
    pp += __shfl_xor(pp, 16, 64);
    qq += __shfl_xor(qq, 32, 64);
    pp += __shfl_xor(pp, 32, 64);
    float rr = dpp_xor1(qq);

    if (quad == 0 && !(l15 & 1)) {
      int e = (rowbase + l15) >> 1;
      float n1 = fmaxf(sqrtf(qq), 1e-8f);
      float n2 = fmaxf(sqrtf(rr), 1e-8f);
      float w = (pp / (n1 * n2) + 1.f) * 0.5f;
      ew_out[e] = w;
      atomicAdd(deg + eidx[e], w);
      atomicAdd(cnt + eidx[EE + e], 1);
    }
  }
}

// ---------------- features fp32 -> bf16 ----------------
__global__ __launch_bounds__(256) void fconv_kernel(const float* __restrict__ src,
                                                    unsigned short* __restrict__ dst) {
  size_t i = ((size_t)blockIdx.x * 256 + threadIdx.x) * 8;
  float4 a = *(const float4*)(src + i);
  float4 b = *(const float4*)(src + i + 4);
  union { ushort8 s; unsigned u[4]; } o;
  o.u[0] = f2bf2(a.x, a.y); o.u[1] = f2bf2(a.z, a.w);
  o.u[2] = f2bf2(b.x, b.y); o.u[3] = f2bf2(b.z, b.w);
  *(ushort8*)(dst + i) = o.s;
}

// ---------------- weights: transpose 256x256 chunks, fp32 -> bf16, Cheb fold ----------------
// Chebyshev identity fold: h = x(W0-W2) + Tx1*W1 + (P*Tx1)*(2*W2) -- exact algebra,
// lets prop2 be a pure SpMM (no sub-read, no subtract).
__global__ __launch_bounds__(256) void wconv_kernel(
    const float* __restrict__ cheb_w, const float* __restrict__ cls_w1,
    unsigned short* __restrict__ wtc, unsigned short* __restrict__ clsT)
{
  __shared__ unsigned short tile[64][80];
  int z = blockIdx.z;
  const float* src; const float* src2 = nullptr; float scale = 1.f;
  unsigned short* dst; int ldk;
  if (z < 12) {
    int l = z / 3, c = z % 3;
    src = cheb_w + (size_t)z * 65536;
    if (c == 0) src2 = cheb_w + (size_t)(l * 3 + 2) * 65536;  // W0 - W2
    if (c == 2) scale = 2.f;                                   // 2*W2
    dst = wtc + (size_t)l * 196608 + c * 256;
    ldk = 768;
  } else {
    int c = z - 12;
    src = cls_w1 + (size_t)c * 65536;
    dst = clsT + c * 256;
    ldk = 1024;
  }
  int t = threadIdx.x;
  int k0 = blockIdx.x * 64, n0 = blockIdx.y * 64;
#pragma unroll
  for (int pass = 0; pass < 4; pass++) {
    int kk = pass * 16 + (t >> 4);
    int nl = (t & 15) * 4;
    size_t offe = (size_t)(k0 + kk) * 256 + n0 + nl;
    float4 v = *(const float4*)(src + offe);
    if (src2) {
      float4 v2 = *(const float4*)(src2 + offe);
      v.x -= v2.x; v.y -= v2.y; v.z -= v2.z; v.w -= v2.w;
    } else if (scale != 1.f) {
      v.x *= scale; v.y *= scale; v.z *= scale; v.w *= scale;
    }
    tile[nl + 0][kk] = f2bf(v.x);
    tile[nl + 1][kk] = f2bf(v.y);
    tile[nl + 2][kk] = f2bf(v.z);
    tile[nl + 3][kk] = f2bf(v.w);
  }
  __syncthreads();
  int nl = t >> 2, kc = (t & 3) * 16;
  ushort8 v0 = *(const ushort8*)&tile[nl][kc];
  ushort8 v1 = *(const ushort8*)&tile[nl][kc + 8];
  unsigned short* dp = dst + (size_t)(n0 + nl) * ldk + k0 + kc;
  *(ushort8*)dp = v0;
  *(ushort8*)(dp + 8) = v1;
}

// ---------------- exclusive scan of in-degree counts (padded to x4) ----------------
__global__ __launch_bounds__(1024) void scan_kernel(const int* __restrict__ cnt, int* __restrict__ ptr) {
  __shared__ int sums[1024];
  int tid = threadIdx.x;
  const int n = NN;
  const int chunk = (n + 1023) / 1024;
  int base = tid * chunk;
  int s = 0;
  for (int i = 0; i < chunk; i++) {
    int idx = base + i;
    if (idx < n) s += (cnt[idx] + 3) & ~3;
  }
  sums[tid] = s;
  __syncthreads();
  for (int off = 1; off < 1024; off <<= 1) {
    int v = (tid >= off) ? sums[tid - off] : 0;
    __syncthreads();
    sums[tid] += v;
    __syncthreads();
  }
  int run = (tid == 0) ? 0 : sums[tid - 1];
  for (int i = 0; i < chunk; i++) {
    int idx = base + i;
    if (idx < n) { ptr[idx] = run; run += (cnt[idx] + 3) & ~3; }
  }
  if (tid == 1023) ptr[n] = run;
}

// ---------------- degree histogram: per-block LDS aggregate -> few global atomics ----------------
__global__ __launch_bounds__(256) void hist_kernel(const int* __restrict__ cnt,
                                                   int* __restrict__ hist) {
  __shared__ int lh[64];
  int tid = threadIdx.x;
  if (tid < 64) lh[tid] = 0;
  __syncthreads();
  int i = blockIdx.x * 256 + tid;
  if (i < NN) {
    int b = (cnt[i] + 3) >> 2; if (b > 63) b = 63;
    atomicAdd(&lh[b], 1);
  }
  __syncthreads();
  if (tid < 64 && lh[tid]) atomicAdd(&hist[tid], lh[tid]);
}

// ---------------- 64-bin exclusive scan (1 wave) + zero binfill ----------------
__global__ void binscan_kernel(const int* __restrict__ hist,
                               int* __restrict__ binbase, int* __restrict__ binfill) {
  int tid = threadIdx.x;   // 64 threads
  int v = hist[tid];
  int x = v;
#pragma unroll
  for (int off = 1; off < 64; off <<= 1) {
    int y = __shfl_up(x, off, 64);
    if (tid >= off) x += y;
  }
  binbase[tid] = x - v;
  binfill[tid] = 0;
}

// ---------------- scatter node ids into degree-sorted order (block-aggregated) ----------------
__global__ __launch_bounds__(256) void perm_kernel(const int* __restrict__ cnt,
                                                   const int* __restrict__ binbase,
                                                   int* __restrict__ binfill,
                                                   int* __restrict__ perm) {
  __shared__ int lh[64], lbase[64];
  int tid = threadIdx.x;
  if (tid < 64) lh[tid] = 0;
  __syncthreads();
  int i = blockIdx.x * 256 + tid;
  int b = 0, local = 0;
  bool valid = (i < NN);
  if (valid) {
    b = (cnt[i] + 3) >> 2; if (b > 63) b = 63;
    local = atomicAdd(&lh[b], 1);        // LDS atomic: cheap
  }
  __syncthreads();
  if (tid < 64 && lh[tid]) lbase[tid] = atomicAdd(&binfill[tid], lh[tid]);  // 1/block/bin
  __syncthreads();
  if (valid) perm[binbase[b] + lbase[b] + local] = i;
}

// ---------------- CSR fill; packed (idx<<16 | bf16 val) per edge slot ----------------
// NN < 32768 so idx fits 15 bits; cval ~0.01 magnitude, bf16 rel-err 2^-9 on a weight
// that multiplies already-bf16 features summed in fp32 -- inside existing error budget.
// Pad slots are memset-0: row 0 x weight 0 = exact no-op.
__global__ void fill_kernel(const int* __restrict__ eidx, const float* __restrict__ ew,
                            const float* __restrict__ deg, const int* __restrict__ ptr,
                            int* __restrict__ fill, unsigned* __restrict__ epack) {
  int e = blockIdx.x * 256 + threadIdx.x;
  if (e < EE) {
    int r = eidx[e], c = eidx[EE + e];
    float dr = deg[r], dc = deg[c];
    float ir = dr > 0.f ? 1.f / sqrtf(fmaxf(dr, 1e-30f)) : 0.f;
    float ic = dc > 0.f ? 1.f / sqrtf(fmaxf(dc, 1e-30f)) : 0.f;
    float nv = -ir * ew[e] * ic;
    int pos = ptr[c] + atomicAdd(&fill[c], 1);
    epack[pos] = ((unsigned)r << 16) | (unsigned short)f2bf(nv);
  }
}

// ---------------- sparse prop (bf16, 8-way XCD slice, degree-binned, depth-2) ----------------
// y[c] = sum val*x[row]. Footprint push (round-10 lever, completed): packed edge stream
// 1.92 MB + 32-ch x-slice 1.28 MB = 3.2 MB per XCD < 4 MB L2 -> gathers L2-resident.
// colslice = bid&7 maps 1:1 to round-robin XCD dispatch. 4 lanes/node x 8ch (16B/lane,
// 64B/laneset gather segment). perm[] degree-binning keeps trip counts uniform.
__global__ __launch_bounds__(256) void prop_kernel(
    const unsigned short* __restrict__ x, int ldx,
    const unsigned* __restrict__ epack,
    const int* __restrict__ ptr, const int* __restrict__ perm,
    unsigned short* __restrict__ y, int ldy)
{
  int colslice = blockIdx.x & 7;                 // 0..7 == XCD (round-robin dispatch)
  int chunk = blockIdx.x >> 3;                   // 0..312
  int ci = chunk * 64 + (threadIdx.x >> 2);
  if (ci >= NN) return;
  int c = perm[ci];
  int d = colslice * 32 + (threadIdx.x & 3) * 8;
  int p0 = ptr[c], p1 = ptr[c + 1];
  float a[8] = {0.f, 0.f, 0.f, 0.f, 0.f, 0.f, 0.f, 0.f};

#define PLOAD(P, PK, V0, V1, V2, V3)                                    \
  do {                                                                  \
    PK = *(const uint4*)(epack + (P));                                  \
    V0 = *(const ushort8*)(x + (size_t)(PK.x >> 16) * ldx + d);         \
    V1 = *(const ushort8*)(x + (size_t)(PK.y >> 16) * ldx + d);         \
    V2 = *(const ushort8*)(x + (size_t)(PK.z >> 16) * ldx + d);         \
    V3 = *(const ushort8*)(x + (size_t)(PK.w >> 16) * ldx + d);         \
  } while (0)

#define PACC(PK, V0, V1, V2, V3)                                        \
  do {                                                                  \
    float w0 = bf2f((unsigned short)(PK.x & 0xffffu));                  \
    float w1 = bf2f((unsigned short)(PK.y & 0xffffu));                  \
    float w2 = bf2f((unsigned short)(PK.z & 0xffffu));                  \
    float w3 = bf2f((unsigned short)(PK.w & 0xffffu));                  \
    _Pragma("unroll")                                                   \
    for (int j = 0; j < 8; j++)                                         \
      a[j] += w0 * bf2f(V0[j]) + w1 * bf2f(V1[j]) +                     \
              w2 * bf2f(V2[j]) + w3 * bf2f(V3[j]);                      \
  } while (0)

  if (p0 < p1) {
    int n4 = (p1 - p0) >> 2;
    uint4 kA, kB;
    ushort8 vA0, vA1, vA2, vA3, vB0, vB1, vB2, vB3;
    PLOAD(p0, kA, vA0, vA1, vA2, vA3);
    if (n4 == 1) {
      PACC(kA, vA0, vA1, vA2, vA3);
    } else {
      PLOAD(p0 + 4, kB, vB0, vB1, vB2, vB3);
      int p = p0 + 8;
      if (n4 & 1) {                       // consume one to make remaining even
        PACC(kA, vA0, vA1, vA2, vA3);
        PLOAD(p, kA, vA0, vA1, vA2, vA3);
        p += 4;
      }
      for (; p < p1; p += 8) {
        PACC(kA, vA0, vA1, vA2, vA3);
        PLOAD(p, kA, vA0, vA1, vA2, vA3);
        PACC(kB, vB0, vB1, vB2, vB3);
        PLOAD(p + 4, kB, vB0, vB1, vB2, vB3);
      }
      PACC(kA, vA0, vA1, vA2, vA3);
      PACC(kB, vB0, vB1, vB2, vB3);
    }
  }
#undef PLOAD
#undef PACC

  union { ushort8 s; unsigned u[4]; } o;
#pragma unroll
  for (int j = 0; j < 8; j += 2)
    o.u[j >> 1] = f2bf2(a[j], a[j + 1]);
  *(ushort8*)(y + (size_t)c * ldy + d) = o.s;
}

// ---------------- bf16 MFMA GEMM: C = post( sum_c A_c @ B_c ) ----------------
// launch_bounds(256,4): 12 KB LDS -> 4 blocks/CU. XCD-swizzled blockIdx.x (T1).
__global__ __launch_bounds__(256, 4) void mgemm_kernel(
    const unsigned short* A0, const unsigned short* A1,
    const unsigned short* A2, const unsigned short* A3,
    int l0, int l1, int l2, int l3, int nchunks,
    const unsigned short* __restrict__ BT, int ldbt,
    unsigned short* __restrict__ Cb, float* __restrict__ Cf, int ldc, int M,
    const float* __restrict__ bias, const float* __restrict__ bng,
    const float* __restrict__ bnb)
{
  __shared__ short As[4 * 64 * 8];
  __shared__ short Bs[4 * 128 * 8];
  int tid = threadIdx.x;
  int lane = tid & 63;
  int wv = tid >> 6;
  int l15 = lane & 15, quad = lane >> 4;
  int wr = wv >> 1, wc = wv & 1;
  int bidx = xcd_swizzle(blockIdx.x, gridDim.x);
  int m0 = bidx * 64, n0 = blockIdx.y * 128;

  const unsigned short* Ap[4] = {A0, A1, A2, A3};
  int Al[4] = {l0, l1, l2, l3};

  int arow = tid & 63, ac = tid >> 6;
  int brow = tid & 127, bc = tid >> 7;

  floatx4 acc[2][4];
#pragma unroll
  for (int mi = 0; mi < 2; mi++)
#pragma unroll
    for (int nj = 0; nj < 4; nj++) acc[mi][nj] = (floatx4){0.f, 0.f, 0.f, 0.f};

  for (int c = 0; c < nchunks; c++) {
    const unsigned short* Abase = Ap[c] + (size_t)(m0 + arow) * Al[c] + ac * 8;
    const unsigned short* Bbase = BT + (size_t)(n0 + brow) * ldbt + c * 256 + bc * 8;
#pragma unroll 1
    for (int kb = 0; kb < 256; kb += 32) {
      __syncthreads();
      gl_lds16(Abase + kb, &As[tid * 8]);
      gl_lds16(Bbase + kb, &Bs[tid * 8]);
      gl_lds16(Bbase + 16 + kb, &Bs[(tid + 256) * 8]);
      __syncthreads();
      short8 af[2], bfv[4];
#pragma unroll
      for (int mi = 0; mi < 2; mi++)
        af[mi] = *(const short8*)&As[(quad * 64 + wr * 32 + mi * 16 + l15) * 8];
#pragma unroll
      for (int nj = 0; nj < 4; nj++)
        bfv[nj] = *(const short8*)&Bs[(quad * 128 + wc * 64 + nj * 16 + l15) * 8];
#pragma unroll
      for (int nj = 0; nj < 4; nj++)
#pragma unroll
        for (int mi = 0; mi < 2; mi++)
          acc[mi][nj] = __builtin_amdgcn_mfma_f32_16x16x32_bf16(af[mi], bfv[nj], acc[mi][nj], 0, 0, 0);
    }
  }

  if (Cb) {
#pragma unroll
    for (int mi = 0; mi < 2; mi++)
#pragma unroll
      for (int r = 0; r < 4; r++) {
        int row = m0 + wr * 32 + mi * 16 + quad * 4 + r;
        if (row < M) {
#pragma unroll
          for (int nj = 0; nj < 4; nj++) {
            int col = n0 + wc * 64 + nj * 16 + l15;
            Cb[(size_t)row * ldc + col] = (unsigned short)f2bf(fmaxf(acc[mi][nj][r], 0.f));
          }
        }
      }
  } else {
    float bs[4], g[4], bb[4];
#pragma unroll
    for (int nj = 0; nj < 4; nj++) {
      int col = n0 + wc * 64 + nj * 16 + l15;
      bs[nj] = bias[col]; g[nj] = bng[col] * RSBN; bb[nj] = bnb[col];
    }
#pragma unroll
    for (int mi = 0; mi < 2; mi++)
#pragma unroll
      for (int r = 0; r < 4; r++) {
        int row = m0 + wr * 32 + mi * 16 + quad * 4 + r;
        if (row < M) {
#pragma unroll
          for (int nj = 0; nj < 4; nj++) {
            int col = n0 + wc * 64 + nj * 16 + l15;
            float v = fmaxf(acc[mi][nj][r] + bs[nj], 0.f) * g[nj] + bb[nj];
            Cf[(size_t)row * ldc + col] = v;
          }
        }
      }
  }
}

// ---------------- final 256x2 matvec per node ----------------
__global__ __launch_bounds__(256) void logit_kernel(
    const float* __restrict__ z, const float* __restrict__ w2,
    const float* __restrict__ b2, float* __restrict__ out)
{
  int node = blockIdx.x * 4 + (threadIdx.x >> 6);
  if (node >= NN) return;
  int lane = threadIdx.x & 63;
  int k = lane * 4;
  float4 zv = *(const float4*)(z + (size_t)node * 256 + k);
  float4 wa = *(const float4*)(w2 + k * 2);
  float4 wb = *(const float4*)(w2 + k * 2 + 4);
  float a0 = zv.x * wa.x + zv.y * wa.z + zv.z * wb.x + zv.w * wb.z;
  float a1 = zv.x * wa.y + zv.y * wa.w + zv.z * wb.y + zv.w * wb.w;
#pragma unroll
  for (int m = 32; m >= 1; m >>= 1) {
    a0 += __shfl_xor(a0, m, 64);
    a1 += __shfl_xor(a1, m, 64);
  }
  if (lane == 0) {
    out[(size_t)node * 2]     = a0 + b2[0];
    out[(size_t)node * 2 + 1] = a1 + b2[1];
  }
}

extern "C" void kernel_launch(void* const* d_in, const int* in_sizes, int n_in,
                              void* d_out, int out_size, void* d_ws, size_t ws_size,
                              hipStream_t stream) {
  const float* features = (const float*)d_in[0];
  const int*   eidx     = (const int*)d_in[1];
  const float* xin      = (const float*)d_in[2];
  const float* cheb_w   = (const float*)d_in[3];
  const float* en_w1    = (const float*)d_in[4];
  const float* en_b1    = (const float*)d_in[5];
  const float* en_g1    = (const float*)d_in[6];
  const float* en_be1   = (const float*)d_in[7];
  const float* en_w2    = (const float*)d_in[8];
  const float* en_b2    = (const float*)d_in[9];
  const float* cls_w1   = (const float*)d_in[10];
  const float* cls_b1   = (const float*)d_in[11];
  const float* cls_g    = (const float*)d_in[12];
  const float* cls_b    = (const float*)d_in[13];
  const float* cls_w2   = (const float*)d_in[14];
  const float* cls_b2   = (const float*)d_in[15];
  float* out = (float*)d_out;

  char* ws = (char*)d_ws;
  size_t off = 0;
  auto alloc = [&](size_t bytes) -> void* {
    void* p = ws + off;
    off += (bytes + 255) & ~(size_t)255;
    return p;
  };
  const int CSRN = EE + 4 * NN;   // padded CSR capacity
  float* deg  = (float*)alloc((size_t)NN * 4);
  int*   cnt  = (int*)  alloc((size_t)NN * 4);
  int*   fil  = (int*)  alloc((size_t)NN * 4);
  int*   hist = (int*)  alloc(64 * 4);
  unsigned* epack = (unsigned*)alloc((size_t)CSRN * 4);
  size_t zero_len = off;                       // deg+cnt+fil+hist+epack zeroed
  int*   ptr  = (int*)  alloc((size_t)(NN + 1) * 4);
  int*   perm = (int*)  alloc((size_t)NN * 4);
  int*   binbase = (int*)alloc(64 * 4);
  int*   binfill = (int*)alloc(64 * 4);
  unsigned short* featb = (unsigned short*)alloc((size_t)NN * 256 * 2);
  unsigned short* Tx1   = (unsigned short*)alloc((size_t)NN * 256 * 2);
  unsigned short* Tx2   = (unsigned short*)alloc((size_t)NN * 256 * 2);
  unsigned short* jk    = (unsigned short*)alloc((size_t)NN * 1024 * 2);
  float* zbuf = (float*)alloc((size_t)NN * 256 * 4);
  unsigned short* wtc   = (unsigned short*)alloc((size_t)4 * 196608 * 2);
  unsigned short* clsT  = (unsigned short*)alloc((size_t)256 * 1024 * 2);
  unsigned short* ewf   = (unsigned short*)alloc((size_t)20992 * 2);
  alloc(262144);   // overread pad for GEMM tail blocks

  float* ew = out + (size_t)NN * 2;   // edge-weight output doubles as scratch

  hipMemsetAsync(deg, 0, zero_len, stream);

  ewconv_kernel<<<1, 256, 0, stream>>>(en_w1, en_w2, en_g1, en_be1, en_b1, en_b2, ewf);
  edge_kernel<<<3125, 512, 0, stream>>>(xin, eidx, ewf, ew, deg, cnt);
  fconv_kernel<<<2500, 256, 0, stream>>>(features, featb);
  wconv_kernel<<<dim3(4, 4, 16), 256, 0, stream>>>(cheb_w, cls_w1, wtc, clsT);
  scan_kernel<<<1, 1024, 0, stream>>>(cnt, ptr);
  hist_kernel<<<(NN + 255) / 256, 256, 0, stream>>>(cnt, hist);
  binscan_kernel<<<1, 64, 0, stream>>>(hist, binbase, binfill);
  perm_kernel<<<(NN + 255) / 256, 256, 0, stream>>>(cnt, binbase, binfill, perm);
  fill_kernel<<<(EE + 255) / 256, 256, 0, stream>>>(eidx, ew, deg, ptr, fil, epack);

  dim3 ggrid(313, 2);
  for (int i = 0; i < 4; i++) {
    const unsigned short* x = (i == 0) ? featb : (jk + (size_t)(i - 1) * 256);
    int ldx = (i == 0) ? 256 : 1024;
    prop_kernel<<<313 * 8, 256, 0, stream>>>(x, ldx, epack, ptr, perm, Tx1, 256);
    prop_kernel<<<313 * 8, 256, 0, stream>>>(Tx1, 256, epack, ptr, perm, Tx2, 256);
    mgemm_kernel<<<ggrid, 256, 0, stream>>>(x, Tx1, Tx2, nullptr, ldx, 256, 256, 0, 3,
                                            wtc + (size_t)i * 196608, 768,
                                            jk + (size_t)i * 256, nullptr, 1024, NN,
                                            nullptr, nullptr, nullptr);
  }

  mgemm_kernel<<<ggrid, 256, 0, stream>>>(jk, jk + 256, jk + 512, jk + 768,
                                          1024, 1024, 1024, 1024, 4, clsT, 1024,
                                          nullptr, zbuf, 256, NN,
                                          cls_b1, cls_g, cls_b);
  logit_kernel<<<NN / 4, 256, 0, stream>>>(zbuf, cls_w2, cls_b2, out);
}

// Round 12
// 623.695 us; speedup vs baseline: 1.1065x; 1.1065x over previous
//
#include <hip/hip_runtime.h>
#include <hip/hip_bf16.h>

#define NN 20000
#define EE 400000
#define RSBN 0.9999950000374997f   // 1/sqrt(1+1e-5)

typedef __attribute__((ext_vector_type(8))) short short8;
typedef __attribute__((ext_vector_type(8))) unsigned short ushort8;
typedef __attribute__((ext_vector_type(4))) short bf4;
typedef __attribute__((ext_vector_type(4))) float floatx4;

__device__ __forceinline__ short f2bf(float f) {
  union { float f; unsigned u; } v; v.f = f;
  unsigned r = v.u + 0x7fffu + ((v.u >> 16) & 1u);   // RNE
  return (short)(r >> 16);
}
__device__ __forceinline__ unsigned f2bf2(float x, float y) {   // packed cvt
  union { __hip_bfloat162 h; unsigned u; } v;
  v.h = __float22bfloat162_rn(make_float2(x, y));
  return v.u;
}
__device__ __forceinline__ float bf2f(unsigned short u) {
  union { unsigned u; float f; } v; v.u = ((unsigned)u) << 16;
  return v.f;
}
__device__ __forceinline__ void gl_lds16(const void* g, void* l) {
  __builtin_amdgcn_global_load_lds(
      (const __attribute__((address_space(1))) unsigned*)g,
      (__attribute__((address_space(3))) unsigned*)l, 16, 0, 0);
}

__device__ __forceinline__ floatx4 mfma16(bf4 a, bf4 b, floatx4 c) {
#if __has_builtin(__builtin_amdgcn_mfma_f32_16x16x16bf16_1k)
  return __builtin_amdgcn_mfma_f32_16x16x16bf16_1k(a, b, c, 0, 0, 0);
#else
  floatx4 d;
  asm volatile("v_mfma_f32_16x16x16_bf16 %0, %1, %2, %3"
               : "=&v"(d) : "v"(a), "v"(b), "v"(c));
  return d;
#endif
}

// lane^1 exchange via DPP quad_perm(1,0,3,2): full-rate VALU, no DS-pipe traffic
__device__ __forceinline__ float dpp_xor1(float x) {
  union { float f; int i; } a, b;
  a.f = x;
  b.i = __builtin_amdgcn_update_dpp(0, a.i, 0xB1, 0xF, 0xF, false);
  return b.f;
}

// bijective XCD-aware remap of a 1D block index (m204 formula)
__device__ __forceinline__ int xcd_swizzle(int bid, int nwg) {
  int q = nwg >> 3, r = nwg & 7;
  int x = bid & 7, o = bid >> 3;
  return (x < r ? x * (q + 1) : r * (q + 1) + (x - r) * q) + o;
}

// ---------------- edge-parser weights -> fragment-layout bf16 + folded consts ----------------
__global__ __launch_bounds__(256) void ewconv_kernel(
    const float* __restrict__ w1, const float* __restrict__ w2,
    const float* __restrict__ g1, const float* __restrict__ be1,
    const float* __restrict__ b1, const float* __restrict__ b2,
    unsigned short* __restrict__ ewf)
{
  int tid = threadIdx.x;
#pragma unroll
  for (int i = 0; i < 16; i++) {
    int idx = i * 256 + tid;
    int k = idx >> 7, n = idx & 127;
    int pos = ((n >> 4) * 64 + (k >> 3) * 16 + (n & 15)) * 8 + (k & 7);
    ewf[pos] = f2bf(w1[idx]);
  }
#pragma unroll
  for (int i = 0; i < 64; i++) {
    int idx = i * 256 + tid;
    int k = idx >> 7, n = idx & 127;
    int u = k >> 4, q = (k >> 2) & 3, j = k & 3;
    int t = n >> 4, l = n & 15;
    int pos = (((u * 8 + t) * 4 + q) * 16 + l) * 4 + j;
    ewf[4096 + pos] = f2bf(w2[idx] * g1[k] * RSBN);   // BN scale folded
  }
  float* fb = (float*)(ewf + 20480);
  if (tid < 128) {
    fb[tid] = b1[tid];
    float acc = b2[tid];
    for (int k = 0; k < 128; k++) acc += be1[k] * w2[k * 128 + tid] * g1[k] * RSBN;
    fb[128 + tid] = acc;
  }
}

// ---------------- edge parser + edge weight (swapped MFMA, 2 tiles/wave) ----------------
// 2-tile version (round 7, counter-verified ~73.5 us). launch_bounds(512,4) = 128 VGPR
// cap (round-2 spill lesson: past the cap, accumulators spill -> 25x scratch traffic).
__global__ __launch_bounds__(512, 4) void edge_kernel(
    const float* __restrict__ xin, const int* __restrict__ eidx,
    const unsigned short* __restrict__ ewf,
    float* __restrict__ ew_out,
    float* __restrict__ deg, int* __restrict__ cnt)
{
  __shared__ short wbuf[20992];

  int tid = threadIdx.x;
  int lane = tid & 63;
  int wv = tid >> 6;
  int l15 = lane & 15;
  int quad = lane >> 4;

#pragma unroll
  for (int i = 0; i < 5; i++)
    gl_lds16(ewf + (i * 512 + tid) * 8, &wbuf[(i * 512 + tid) * 8]);
  if (tid < 64)
    gl_lds16(ewf + (2560 + tid) * 8, &wbuf[(2560 + tid) * 8]);

  const short* w1f = wbuf;
  const short* w2f = wbuf + 4096;

  int rowA = blockIdx.x * 256 + wv * 16;
  int rowB = rowA + 128;

  short8 afA, afB;
  {
    const float* xpA = xin + (size_t)(rowA + l15) * 32 + quad * 8;
    const float* xpB = xin + (size_t)(rowB + l15) * 32 + quad * 8;
    float4 a0 = *(const float4*)xpA;
    float4 a1 = *(const float4*)(xpA + 4);
    float4 b0 = *(const float4*)xpB;
    float4 b1v = *(const float4*)(xpB + 4);
    union { short8 s; unsigned u[4]; } a, b;
    a.u[0] = f2bf2(a0.x, a0.y); a.u[1] = f2bf2(a0.z, a0.w);
    a.u[2] = f2bf2(a1.x, a1.y); a.u[3] = f2bf2(a1.z, a1.w);
    b.u[0] = f2bf2(b0.x, b0.y); b.u[1] = f2bf2(b0.z, b0.w);
    b.u[2] = f2bf2(b1v.x, b1v.y); b.u[3] = f2bf2(b1v.z, b1v.w);
    afA = a.s; afB = b.s;
  }

  __syncthreads();

  const float* fb = (const float*)(wbuf + 20480);

  floatx4 acc1A[8], acc1B[8];
#pragma unroll
  for (int t = 0; t < 8; t++) {
    floatx4 z = *(const floatx4*)&fb[t * 16 + quad * 4];   // b1 rows (tile-independent)
    short8 w1v = *(const short8*)&w1f[(t * 64 + lane) * 8];
    acc1A[t] = __builtin_amdgcn_mfma_f32_16x16x32_bf16(w1v, afA, z, 0, 0, 0);
    acc1B[t] = __builtin_amdgcn_mfma_f32_16x16x32_bf16(w1v, afB, z, 0, 0, 0);
  }

  bf4 pbA[8], pbB[8];
#pragma unroll
  for (int u = 0; u < 8; u++) {
    union { bf4 s; unsigned w[2]; } oa, ob;
    oa.w[0] = f2bf2(fmaxf(acc1A[u][0], 0.f), fmaxf(acc1A[u][1], 0.f));
    oa.w[1] = f2bf2(fmaxf(acc1A[u][2], 0.f), fmaxf(acc1A[u][3], 0.f));
    ob.w[0] = f2bf2(fmaxf(acc1B[u][0], 0.f), fmaxf(acc1B[u][1], 0.f));
    ob.w[1] = f2bf2(fmaxf(acc1B[u][2], 0.f), fmaxf(acc1B[u][3], 0.f));
    pbA[u] = oa.s; pbB[u] = ob.s;
  }

  floatx4 acc2A[8], acc2B[8];
#pragma unroll
  for (int t = 0; t < 8; t++) {
    floatx4 z2 = *(const floatx4*)&fb[128 + t * 16 + quad * 4];   // folded b2
    acc2A[t] = z2; acc2B[t] = z2;
  }
#pragma unroll
  for (int u = 0; u < 8; u++)
#pragma unroll
    for (int t = 0; t < 8; t++) {
      bf4 a4 = *(const bf4*)&w2f[((u * 8 + t) * 64 + lane) * 4];
      acc2A[t] = mfma16(a4, pbA[u], acc2A[t]);
      acc2B[t] = mfma16(a4, pbB[u], acc2B[t]);
    }

#pragma unroll
  for (int tile = 0; tile < 2; tile++) {
    floatx4* acc2 = tile ? acc2B : acc2A;
    int rowbase = tile ? rowB : rowA;
    float qq = 0.f, pp = 0.f;
#pragma unroll
    for (int t = 0; t < 8; t++)
#pragma unroll
      for (int r = 0; r < 4; r++) {
        float h = acc2[t][r];
        float hp = dpp_xor1(h);
        qq += h * h;
        pp += h * hp;
      }
    qq += __shfl_xor(qq, 16, 64);
    pp += __shfl_xor(pp, 16, 64);
    qq += __shfl_xor(qq, 32, 64);
    pp += __shfl_xor(pp, 32, 64);
    float rr = dpp_xor1(qq);

    if (quad == 0 && !(l15 & 1)) {
      int e = (rowbase + l15) >> 1;
      float n1 = fmaxf(sqrtf(qq), 1e-8f);
      float n2 = fmaxf(sqrtf(rr), 1e-8f);
      float w = (pp / (n1 * n2) + 1.f) * 0.5f;
      ew_out[e] = w;
      atomicAdd(deg + eidx[e], w);
      atomicAdd(cnt + eidx[EE + e], 1);
    }
  }
}

// ---------------- features fp32 -> bf16 ----------------
__global__ __launch_bounds__(256) void fconv_kernel(const float* __restrict__ src,
                                                    unsigned short* __restrict__ dst) {
  size_t i = ((size_t)blockIdx.x * 256 + threadIdx.x) * 8;
  float4 a = *(const float4*)(src + i);
  float4 b = *(const float4*)(src + i + 4);
  union { ushort8 s; unsigned u[4]; } o;
  o.u[0] = f2bf2(a.x, a.y); o.u[1] = f2bf2(a.z, a.w);
  o.u[2] = f2bf2(b.x, b.y); o.u[3] = f2bf2(b.z, b.w);
  *(ushort8*)(dst + i) = o.s;
}

// ---------------- weights: transpose 256x256 chunks, fp32 -> bf16, Cheb fold ----------------
// Chebyshev identity fold: h = x(W0-W2) + Tx1*W1 + (P*Tx1)*(2*W2) -- exact algebra,
// lets prop2 be a pure SpMM (no sub-read, no subtract).
__global__ __launch_bounds__(256) void wconv_kernel(
    const float* __restrict__ cheb_w, const float* __restrict__ cls_w1,
    unsigned short* __restrict__ wtc, unsigned short* __restrict__ clsT)
{
  __shared__ unsigned short tile[64][80];
  int z = blockIdx.z;
  const float* src; const float* src2 = nullptr; float scale = 1.f;
  unsigned short* dst; int ldk;
  if (z < 12) {
    int l = z / 3, c = z % 3;
    src = cheb_w + (size_t)z * 65536;
    if (c == 0) src2 = cheb_w + (size_t)(l * 3 + 2) * 65536;  // W0 - W2
    if (c == 2) scale = 2.f;                                   // 2*W2
    dst = wtc + (size_t)l * 196608 + c * 256;
    ldk = 768;
  } else {
    int c = z - 12;
    src = cls_w1 + (size_t)c * 65536;
    dst = clsT + c * 256;
    ldk = 1024;
  }
  int t = threadIdx.x;
  int k0 = blockIdx.x * 64, n0 = blockIdx.y * 64;
#pragma unroll
  for (int pass = 0; pass < 4; pass++) {
    int kk = pass * 16 + (t >> 4);
    int nl = (t & 15) * 4;
    size_t offe = (size_t)(k0 + kk) * 256 + n0 + nl;
    float4 v = *(const float4*)(src + offe);
    if (src2) {
      float4 v2 = *(const float4*)(src2 + offe);
      v.x -= v2.x; v.y -= v2.y; v.z -= v2.z; v.w -= v2.w;
    } else if (scale != 1.f) {
      v.x *= scale; v.y *= scale; v.z *= scale; v.w *= scale;
    }
    tile[nl + 0][kk] = f2bf(v.x);
    tile[nl + 1][kk] = f2bf(v.y);
    tile[nl + 2][kk] = f2bf(v.z);
    tile[nl + 3][kk] = f2bf(v.w);
  }
  __syncthreads();
  int nl = t >> 2, kc = (t & 3) * 16;
  ushort8 v0 = *(const ushort8*)&tile[nl][kc];
  ushort8 v1 = *(const ushort8*)&tile[nl][kc + 8];
  unsigned short* dp = dst + (size_t)(n0 + nl) * ldk + k0 + kc;
  *(ushort8*)dp = v0;
  *(ushort8*)(dp + 8) = v1;
}

// ---------------- exclusive scan of in-degree counts (padded to x4) ----------------
__global__ __launch_bounds__(1024) void scan_kernel(const int* __restrict__ cnt, int* __restrict__ ptr) {
  __shared__ int sums[1024];
  int tid = threadIdx.x;
  const int n = NN;
  const int chunk = (n + 1023) / 1024;
  int base = tid * chunk;
  int s = 0;
  for (int i = 0; i < chunk; i++) {
    int idx = base + i;
    if (idx < n) s += (cnt[idx] + 3) & ~3;
  }
  sums[tid] = s;
  __syncthreads();
  for (int off = 1; off < 1024; off <<= 1) {
    int v = (tid >= off) ? sums[tid - off] : 0;
    __syncthreads();
    sums[tid] += v;
    __syncthreads();
  }
  int run = (tid == 0) ? 0 : sums[tid - 1];
  for (int i = 0; i < chunk; i++) {
    int idx = base + i;
    if (idx < n) { ptr[idx] = run; run += (cnt[idx] + 3) & ~3; }
  }
  if (tid == 1023) ptr[n] = run;
}

// ---------------- degree histogram: per-block LDS aggregate -> few global atomics ----------------
__global__ __launch_bounds__(256) void hist_kernel(const int* __restrict__ cnt,
                                                   int* __restrict__ hist) {
  __shared__ int lh[64];
  int tid = threadIdx.x;
  if (tid < 64) lh[tid] = 0;
  __syncthreads();
  int i = blockIdx.x * 256 + tid;
  if (i < NN) {
    int b = (cnt[i] + 3) >> 2; if (b > 63) b = 63;
    atomicAdd(&lh[b], 1);
  }
  __syncthreads();
  if (tid < 64 && lh[tid]) atomicAdd(&hist[tid], lh[tid]);
}

// ---------------- 64-bin exclusive scan (1 wave) + zero binfill ----------------
__global__ void binscan_kernel(const int* __restrict__ hist,
                               int* __restrict__ binbase, int* __restrict__ binfill) {
  int tid = threadIdx.x;   // 64 threads
  int v = hist[tid];
  int x = v;
#pragma unroll
  for (int off = 1; off < 64; off <<= 1) {
    int y = __shfl_up(x, off, 64);
    if (tid >= off) x += y;
  }
  binbase[tid] = x - v;
  binfill[tid] = 0;
}

// ---------------- scatter node ids into degree-sorted order (block-aggregated) ----------------
__global__ __launch_bounds__(256) void perm_kernel(const int* __restrict__ cnt,
                                                   const int* __restrict__ binbase,
                                                   int* __restrict__ binfill,
                                                   int* __restrict__ perm) {
  __shared__ int lh[64], lbase[64];
  int tid = threadIdx.x;
  if (tid < 64) lh[tid] = 0;
  __syncthreads();
  int i = blockIdx.x * 256 + tid;
  int b = 0, local = 0;
  bool valid = (i < NN);
  if (valid) {
    b = (cnt[i] + 3) >> 2; if (b > 63) b = 63;
    local = atomicAdd(&lh[b], 1);        // LDS atomic: cheap
  }
  __syncthreads();
  if (tid < 64 && lh[tid]) lbase[tid] = atomicAdd(&binfill[tid], lh[tid]);  // 1/block/bin
  __syncthreads();
  if (valid) perm[binbase[b] + lbase[b] + local] = i;
}

// ---------------- CSR fill; packed (idx<<16 | bf16 val) per edge slot ----------------
// NN < 32768 so idx fits 15 bits; cval ~0.01 magnitude, bf16 rel-err 2^-9 on a weight
// multiplying already-bf16 features summed in fp32 -- inside existing error budget.
// Pad slots memset-0: row 0 x weight 0 = exact no-op.
__global__ void fill_kernel(const int* __restrict__ eidx, const float* __restrict__ ew,
                            const float* __restrict__ deg, const int* __restrict__ ptr,
                            int* __restrict__ fill, unsigned* __restrict__ epack) {
  int e = blockIdx.x * 256 + threadIdx.x;
  if (e < EE) {
    int r = eidx[e], c = eidx[EE + e];
    float dr = deg[r], dc = deg[c];
    float ir = dr > 0.f ? 1.f / sqrtf(fmaxf(dr, 1e-30f)) : 0.f;
    float ic = dc > 0.f ? 1.f / sqrtf(fmaxf(dc, 1e-30f)) : 0.f;
    float nv = -ir * ew[e] * ic;
    int pos = ptr[c] + atomicAdd(&fill[c], 1);
    epack[pos] = ((unsigned)r << 16) | (unsigned short)f2bf(nv);
  }
}

// ---------------- sparse prop (bf16, 4-way XCD slice, degree-binned, depth-2) ----------------
// ROUND-10 PROVEN STRUCTURE (638 us): 64-ch slices -> 128 B gather segments (full L2
// line; round-11's 32-ch/64 B segments wasted half of every fetched line, -52 us).
// Only isolated change vs round-10: packed epack (4 B/edge vs 6 B) -- one load instead
// of two, per-XCD footprint ~3.4 MB.
__global__ __launch_bounds__(256) void prop_kernel(
    const unsigned short* __restrict__ x, int ldx,
    const unsigned* __restrict__ epack,
    const int* __restrict__ ptr, const int* __restrict__ perm,
    unsigned short* __restrict__ y, int ldy)
{
  int sliceid = blockIdx.x & 7;
  int colslice = sliceid >> 1;                       // 0..3  (64 ch = 128 B)
  int chunk = (blockIdx.x >> 3) * 2 + (sliceid & 1); // 0..625
  int ci = chunk * 32 + (threadIdx.x >> 3);
  if (ci >= NN) return;
  int c = perm[ci];
  int d = colslice * 64 + (threadIdx.x & 7) * 8;
  int p0 = ptr[c], p1 = ptr[c + 1];
  float a[8] = {0.f, 0.f, 0.f, 0.f, 0.f, 0.f, 0.f, 0.f};

#define PLOAD(P, PK, V0, V1, V2, V3)                                    \
  do {                                                                  \
    PK = *(const uint4*)(epack + (P));                                  \
    V0 = *(const ushort8*)(x + (size_t)(PK.x >> 16) * ldx + d);         \
    V1 = *(const ushort8*)(x + (size_t)(PK.y >> 16) * ldx + d);         \
    V2 = *(const ushort8*)(x + (size_t)(PK.z >> 16) * ldx + d);         \
    V3 = *(const ushort8*)(x + (size_t)(PK.w >> 16) * ldx + d);         \
  } while (0)

#define PACC(PK, V0, V1, V2, V3)                                        \
  do {                                                                  \
    float w0 = bf2f((unsigned short)(PK.x & 0xffffu));                  \
    float w1 = bf2f((unsigned short)(PK.y & 0xffffu));                  \
    float w2 = bf2f((unsigned short)(PK.z & 0xffffu));                  \
    float w3 = bf2f((unsigned short)(PK.w & 0xffffu));                  \
    _Pragma("unroll")                                                   \
    for (int j = 0; j < 8; j++)                                         \
      a[j] += w0 * bf2f(V0[j]) + w1 * bf2f(V1[j]) +                     \
              w2 * bf2f(V2[j]) + w3 * bf2f(V3[j]);                      \
  } while (0)

  if (p0 < p1) {
    int n4 = (p1 - p0) >> 2;
    uint4 kA, kB;
    ushort8 vA0, vA1, vA2, vA3, vB0, vB1, vB2, vB3;
    PLOAD(p0, kA, vA0, vA1, vA2, vA3);
    if (n4 == 1) {
      PACC(kA, vA0, vA1, vA2, vA3);
    } else {
      PLOAD(p0 + 4, kB, vB0, vB1, vB2, vB3);
      int p = p0 + 8;
      if (n4 & 1) {                       // consume one to make remaining even
        PACC(kA, vA0, vA1, vA2, vA3);
        PLOAD(p, kA, vA0, vA1, vA2, vA3);
        p += 4;
      }
      for (; p < p1; p += 8) {
        PACC(kA, vA0, vA1, vA2, vA3);
        PLOAD(p, kA, vA0, vA1, vA2, vA3);
        PACC(kB, vB0, vB1, vB2, vB3);
        PLOAD(p + 4, kB, vB0, vB1, vB2, vB3);
      }
      PACC(kA, vA0, vA1, vA2, vA3);
      PACC(kB, vB0, vB1, vB2, vB3);
    }
  }
#undef PLOAD
#undef PACC

  union { ushort8 s; unsigned u[4]; } o;
#pragma unroll
  for (int j = 0; j < 8; j += 2)
    o.u[j >> 1] = f2bf2(a[j], a[j + 1]);
  *(ushort8*)(y + (size_t)c * ldy + d) = o.s;
}

// ---------------- bf16 MFMA GEMM: C = post( sum_c A_c @ B_c ) ----------------
// launch_bounds(256,4): 12 KB LDS -> 4 blocks/CU. XCD-swizzled blockIdx.x (T1).
__global__ __launch_bounds__(256, 4) void mgemm_kernel(
    const unsigned short* A0, const unsigned short* A1,
    const unsigned short* A2, const unsigned short* A3,
    int l0, int l1, int l2, int l3, int nchunks,
    const unsigned short* __restrict__ BT, int ldbt,
    unsigned short* __restrict__ Cb, float* __restrict__ Cf, int ldc, int M,
    const float* __restrict__ bias, const float* __restrict__ bng,
    const float* __restrict__ bnb)
{
  __shared__ short As[4 * 64 * 8];
  __shared__ short Bs[4 * 128 * 8];
  int tid = threadIdx.x;
  int lane = tid & 63;
  int wv = tid >> 6;
  int l15 = lane & 15, quad = lane >> 4;
  int wr = wv >> 1, wc = wv & 1;
  int bidx = xcd_swizzle(blockIdx.x, gridDim.x);
  int m0 = bidx * 64, n0 = blockIdx.y * 128;

  const unsigned short* Ap[4] = {A0, A1, A2, A3};
  int Al[4] = {l0, l1, l2, l3};

  int arow = tid & 63, ac = tid >> 6;
  int brow = tid & 127, bc = tid >> 7;

  floatx4 acc[2][4];
#pragma unroll
  for (int mi = 0; mi < 2; mi++)
#pragma unroll
    for (int nj = 0; nj < 4; nj++) acc[mi][nj] = (floatx4){0.f, 0.f, 0.f, 0.f};

  for (int c = 0; c < nchunks; c++) {
    const unsigned short* Abase = Ap[c] + (size_t)(m0 + arow) * Al[c] + ac * 8;
    const unsigned short* Bbase = BT + (size_t)(n0 + brow) * ldbt + c * 256 + bc * 8;
#pragma unroll 1
    for (int kb = 0; kb < 256; kb += 32) {
      __syncthreads();
      gl_lds16(Abase + kb, &As[tid * 8]);
      gl_lds16(Bbase + kb, &Bs[tid * 8]);
      gl_lds16(Bbase + 16 + kb, &Bs[(tid + 256) * 8]);
      __syncthreads();
      short8 af[2], bfv[4];
#pragma unroll
      for (int mi = 0; mi < 2; mi++)
        af[mi] = *(const short8*)&As[(quad * 64 + wr * 32 + mi * 16 + l15) * 8];
#pragma unroll
      for (int nj = 0; nj < 4; nj++)
        bfv[nj] = *(const short8*)&Bs[(quad * 128 + wc * 64 + nj * 16 + l15) * 8];
#pragma unroll
      for (int nj = 0; nj < 4; nj++)
#pragma unroll
        for (int mi = 0; mi < 2; mi++)
          acc[mi][nj] = __builtin_amdgcn_mfma_f32_16x16x32_bf16(af[mi], bfv[nj], acc[mi][nj], 0, 0, 0);
    }
  }

  if (Cb) {
#pragma unroll
    for (int mi = 0; mi < 2; mi++)
#pragma unroll
      for (int r = 0; r < 4; r++) {
        int row = m0 + wr * 32 + mi * 16 + quad * 4 + r;
        if (row < M) {
#pragma unroll
          for (int nj = 0; nj < 4; nj++) {
            int col = n0 + wc * 64 + nj * 16 + l15;
            Cb[(size_t)row * ldc + col] = (unsigned short)f2bf(fmaxf(acc[mi][nj][r], 0.f));
          }
        }
      }
  } else {
    float bs[4], g[4], bb[4];
#pragma unroll
    for (int nj = 0; nj < 4; nj++) {
      int col = n0 + wc * 64 + nj * 16 + l15;
      bs[nj] = bias[col]; g[nj] = bng[col] * RSBN; bb[nj] = bnb[col];
    }
#pragma unroll
    for (int mi = 0; mi < 2; mi++)
#pragma unroll
      for (int r = 0; r < 4; r++) {
        int row = m0 + wr * 32 + mi * 16 + quad * 4 + r;
        if (row < M) {
#pragma unroll
          for (int nj = 0; nj < 4; nj++) {
            int col = n0 + wc * 64 + nj * 16 + l15;
            float v = fmaxf(acc[mi][nj][r] + bs[nj], 0.f) * g[nj] + bb[nj];
            Cf[(size_t)row * ldc + col] = v;
          }
        }
      }
  }
}

// ---------------- final 256x2 matvec per node ----------------
__global__ __launch_bounds__(256) void logit_kernel(
    const float* __restrict__ z, const float* __restrict__ w2,
    const float* __restrict__ b2, float* __restrict__ out)
{
  int node = blockIdx.x * 4 + (threadIdx.x >> 6);
  if (node >= NN) return;
  int lane = threadIdx.x & 63;
  int k = lane * 4;
  float4 zv = *(const float4*)(z + (size_t)node * 256 + k);
  float4 wa = *(const float4*)(w2 + k * 2);
  float4 wb = *(const float4*)(w2 + k * 2 + 4);
  float a0 = zv.x * wa.x + zv.y * wa.z + zv.z * wb.x + zv.w * wb.z;
  float a1 = zv.x * wa.y + zv.y * wa.w + zv.z * wb.y + zv.w * wb.w;
#pragma unroll
  for (int m = 32; m >= 1; m >>= 1) {
    a0 += __shfl_xor(a0, m, 64);
    a1 += __shfl_xor(a1, m, 64);
  }
  if (lane == 0) {
    out[(size_t)node * 2]     = a0 + b2[0];
    out[(size_t)node * 2 + 1] = a1 + b2[1];
  }
}

extern "C" void kernel_launch(void* const* d_in, const int* in_sizes, int n_in,
                              void* d_out, int out_size, void* d_ws, size_t ws_size,
                              hipStream_t stream) {
  const float* features = (const float*)d_in[0];
  const int*   eidx     = (const int*)d_in[1];
  const float* xin      = (const float*)d_in[2];
  const float* cheb_w   = (const float*)d_in[3];
  const float* en_w1    = (const float*)d_in[4];
  const float* en_b1    = (const float*)d_in[5];
  const float* en_g1    = (const float*)d_in[6];
  const float* en_be1   = (const float*)d_in[7];
  const float* en_w2    = (const float*)d_in[8];
  const float* en_b2    = (const float*)d_in[9];
  const float* cls_w1   = (const float*)d_in[10];
  const float* cls_b1   = (const float*)d_in[11];
  const float* cls_g    = (const float*)d_in[12];
  const float* cls_b    = (const float*)d_in[13];
  const float* cls_w2   = (const float*)d_in[14];
  const float* cls_b2   = (const float*)d_in[15];
  float* out = (float*)d_out;

  char* ws = (char*)d_ws;
  size_t off = 0;
  auto alloc = [&](size_t bytes) -> void* {
    void* p = ws + off;
    off += (bytes + 255) & ~(size_t)255;
    return p;
  };
  const int CSRN = EE + 4 * NN;   // padded CSR capacity
  float* deg  = (float*)alloc((size_t)NN * 4);
  int*   cnt  = (int*)  alloc((size_t)NN * 4);
  int*   fil  = (int*)  alloc((size_t)NN * 4);
  int*   hist = (int*)  alloc(64 * 4);
  unsigned* epack = (unsigned*)alloc((size_t)CSRN * 4);
  size_t zero_len = off;                       // deg+cnt+fil+hist+epack zeroed
  int*   ptr  = (int*)  alloc((size_t)(NN + 1) * 4);
  int*   perm = (int*)  alloc((size_t)NN * 4);
  int*   binbase = (int*)alloc(64 * 4);
  int*   binfill = (int*)alloc(64 * 4);
  unsigned short* featb = (unsigned short*)alloc((size_t)NN * 256 * 2);
  unsigned short* Tx1   = (unsigned short*)alloc((size_t)NN * 256 * 2);
  unsigned short* Tx2   = (unsigned short*)alloc((size_t)NN * 256 * 2);
  unsigned short* jk    = (unsigned short*)alloc((size_t)NN * 1024 * 2);
  float* zbuf = (float*)alloc((size_t)NN * 256 * 4);
  unsigned short* wtc   = (unsigned short*)alloc((size_t)4 * 196608 * 2);
  unsigned short* clsT  = (unsigned short*)alloc((size_t)256 * 1024 * 2);
  unsigned short* ewf   = (unsigned short*)alloc((size_t)20992 * 2);
  alloc(262144);   // overread pad for GEMM tail blocks

  float* ew = out + (size_t)NN * 2;   // edge-weight output doubles as scratch

  hipMemsetAsync(deg, 0, zero_len, stream);

  ewconv_kernel<<<1, 256, 0, stream>>>(en_w1, en_w2, en_g1, en_be1, en_b1, en_b2, ewf);
  edge_kernel<<<3125, 512, 0, stream>>>(xin, eidx, ewf, ew, deg, cnt);
  fconv_kernel<<<2500, 256, 0, stream>>>(features, featb);
  wconv_kernel<<<dim3(4, 4, 16), 256, 0, stream>>>(cheb_w, cls_w1, wtc, clsT);
  scan_kernel<<<1, 1024, 0, stream>>>(cnt, ptr);
  hist_kernel<<<(NN + 255) / 256, 256, 0, stream>>>(cnt, hist);
  binscan_kernel<<<1, 64, 0, stream>>>(hist, binbase, binfill);
  perm_kernel<<<(NN + 255) / 256, 256, 0, stream>>>(cnt, binbase, binfill, perm);
  fill_kernel<<<(EE + 255) / 256, 256, 0, stream>>>(eidx, ew, deg, ptr, fil, epack);

  dim3 ggrid(313, 2);
  for (int i = 0; i < 4; i++) {
    const unsigned short* x = (i == 0) ? featb : (jk + (size_t)(i - 1) * 256);
    int ldx = (i == 0) ? 256 : 1024;
    prop_kernel<<<2504, 256, 0, stream>>>(x, ldx, epack, ptr, perm, Tx1, 256);
    prop_kernel<<<2504, 256, 0, stream>>>(Tx1, 256, epack, ptr, perm, Tx2, 256);
    mgemm_kernel<<<ggrid, 256, 0, stream>>>(x, Tx1, Tx2, nullptr, ldx, 256, 256, 0, 3,
                                            wtc + (size_t)i * 196608, 768,
                                            jk + (size_t)i * 256, nullptr, 1024, NN,
                                            nullptr, nullptr, nullptr);
  }

  mgemm_kernel<<<ggrid, 256, 0, stream>>>(jk, jk + 256, jk + 512, jk + 768,
                                          1024, 1024, 1024, 1024, 4, clsT, 1024,
                                          nullptr, zbuf, 256, NN,
                                          cls_b1, cls_g, cls_b);
  logit_kernel<<<NN / 4, 256, 0, stream>>>(zbuf, cls_w2, cls_b2, out);
}

// Round 13
// 620.768 us; speedup vs baseline: 1.1117x; 1.0047x over previous
//
#include <hip/hip_runtime.h>
#include <hip/hip_bf16.h>

#define NN 20000
#define EE 400000
#define RSBN 0.9999950000374997f   // 1/sqrt(1+1e-5)

typedef __attribute__((ext_vector_type(8))) short short8;
typedef __attribute__((ext_vector_type(8))) unsigned short ushort8;
typedef __attribute__((ext_vector_type(4))) short bf4;
typedef __attribute__((ext_vector_type(4))) float floatx4;

__device__ __forceinline__ short f2bf(float f) {
  union { float f; unsigned u; } v; v.f = f;
  unsigned r = v.u + 0x7fffu + ((v.u >> 16) & 1u);   // RNE
  return (short)(r >> 16);
}
__device__ __forceinline__ unsigned f2bf2(float x, float y) {   // packed cvt
  union { __hip_bfloat162 h; unsigned u; } v;
  v.h = __float22bfloat162_rn(make_float2(x, y));
  return v.u;
}
__device__ __forceinline__ float bf2f(unsigned short u) {
  union { unsigned u; float f; } v; v.u = ((unsigned)u) << 16;
  return v.f;
}
__device__ __forceinline__ void gl_lds16(const void* g, void* l) {
  __builtin_amdgcn_global_load_lds(
      (const __attribute__((address_space(1))) unsigned*)g,
      (__attribute__((address_space(3))) unsigned*)l, 16, 0, 0);
}

__device__ __forceinline__ floatx4 mfma16(bf4 a, bf4 b, floatx4 c) {
#if __has_builtin(__builtin_amdgcn_mfma_f32_16x16x16bf16_1k)
  return __builtin_amdgcn_mfma_f32_16x16x16bf16_1k(a, b, c, 0, 0, 0);
#else
  floatx4 d;
  asm volatile("v_mfma_f32_16x16x16_bf16 %0, %1, %2, %3"
               : "=&v"(d) : "v"(a), "v"(b), "v"(c));
  return d;
#endif
}

// lane^1 exchange via DPP quad_perm(1,0,3,2): full-rate VALU, no DS-pipe traffic
__device__ __forceinline__ float dpp_xor1(float x) {
  union { float f; int i; } a, b;
  a.f = x;
  b.i = __builtin_amdgcn_update_dpp(0, a.i, 0xB1, 0xF, 0xF, false);
  return b.f;
}

// bijective XCD-aware remap of a 1D block index (m204 formula)
__device__ __forceinline__ int xcd_swizzle(int bid, int nwg) {
  int q = nwg >> 3, r = nwg & 7;
  int x = bid & 7, o = bid >> 3;
  return (x < r ? x * (q + 1) : r * (q + 1) + (x - r) * q) + o;
}

// ---------------- edge-parser weights -> fragment-layout bf16 + folded consts ----------------
__global__ __launch_bounds__(256) void ewconv_kernel(
    const float* __restrict__ w1, const float* __restrict__ w2,
    const float* __restrict__ g1, const float* __restrict__ be1,
    const float* __restrict__ b1, const float* __restrict__ b2,
    unsigned short* __restrict__ ewf)
{
  int tid = threadIdx.x;
#pragma unroll
  for (int i = 0; i < 16; i++) {
    int idx = i * 256 + tid;
    int k = idx >> 7, n = idx & 127;
    int pos = ((n >> 4) * 64 + (k >> 3) * 16 + (n & 15)) * 8 + (k & 7);
    ewf[pos] = f2bf(w1[idx]);
  }
#pragma unroll
  for (int i = 0; i < 64; i++) {
    int idx = i * 256 + tid;
    int k = idx >> 7, n = idx & 127;
    int u = k >> 4, q = (k >> 2) & 3, j = k & 3;
    int t = n >> 4, l = n & 15;
    int pos = (((u * 8 + t) * 4 + q) * 16 + l) * 4 + j;
    ewf[4096 + pos] = f2bf(w2[idx] * g1[k] * RSBN);   // BN scale folded
  }
  float* fb = (float*)(ewf + 20480);
  if (tid < 128) {
    fb[tid] = b1[tid];
    float acc = b2[tid];
    for (int k = 0; k < 128; k++) acc += be1[k] * w2[k * 128 + tid] * g1[k] * RSBN;
    fb[128 + tid] = acc;
  }
}

// ---------------- edge parser + edge weight (swapped MFMA, 2 tiles/wave) ----------------
// 2-tile version (round 7, counter-verified ~73.5 us). launch_bounds(512,4) = 128 VGPR
// cap (round-2 spill lesson: past the cap, accumulators spill -> 25x scratch traffic).
__global__ __launch_bounds__(512, 4) void edge_kernel(
    const float* __restrict__ xin, const int* __restrict__ eidx,
    const unsigned short* __restrict__ ewf,
    float* __restrict__ ew_out,
    float* __restrict__ deg, int* __restrict__ cnt)
{
  __shared__ short wbuf[20992];

  int tid = threadIdx.x;
  int lane = tid & 63;
  int wv = tid >> 6;
  int l15 = lane & 15;
  int quad = lane >> 4;

#pragma unroll
  for (int i = 0; i < 5; i++)
    gl_lds16(ewf + (i * 512 + tid) * 8, &wbuf[(i * 512 + tid) * 8]);
  if (tid < 64)
    gl_lds16(ewf + (2560 + tid) * 8, &wbuf[(2560 + tid) * 8]);

  const short* w1f = wbuf;
  const short* w2f = wbuf + 4096;

  int rowA = blockIdx.x * 256 + wv * 16;
  int rowB = rowA + 128;

  short8 afA, afB;
  {
    const float* xpA = xin + (size_t)(rowA + l15) * 32 + quad * 8;
    const float* xpB = xin + (size_t)(rowB + l15) * 32 + quad * 8;
    float4 a0 = *(const float4*)xpA;
    float4 a1 = *(const float4*)(xpA + 4);
    float4 b0 = *(const float4*)xpB;
    float4 b1v = *(const float4*)(xpB + 4);
    union { short8 s; unsigned u[4]; } a, b;
    a.u[0] = f2bf2(a0.x, a0.y); a.u[1] = f2bf2(a0.z, a0.w);
    a.u[2] = f2bf2(a1.x, a1.y); a.u[3] = f2bf2(a1.z, a1.w);
    b.u[0] = f2bf2(b0.x, b0.y); b.u[1] = f2bf2(b0.z, b0.w);
    b.u[2] = f2bf2(b1v.x, b1v.y); b.u[3] = f2bf2(b1v.z, b1v.w);
    afA = a.s; afB = b.s;
  }

  __syncthreads();

  const float* fb = (const float*)(wbuf + 20480);

  floatx4 acc1A[8], acc1B[8];
#pragma unroll
  for (int t = 0; t < 8; t++) {
    floatx4 z = *(const floatx4*)&fb[t * 16 + quad * 4];   // b1 rows (tile-independent)
    short8 w1v = *(const short8*)&w1f[(t * 64 + lane) * 8];
    acc1A[t] = __builtin_amdgcn_mfma_f32_16x16x32_bf16(w1v, afA, z, 0, 0, 0);
    acc1B[t] = __builtin_amdgcn_mfma_f32_16x16x32_bf16(w1v, afB, z, 0, 0, 0);
  }

  bf4 pbA[8], pbB[8];
#pragma unroll
  for (int u = 0; u < 8; u++) {
    union { bf4 s; unsigned w[2]; } oa, ob;
    oa.w[0] = f2bf2(fmaxf(acc1A[u][0], 0.f), fmaxf(acc1A[u][1], 0.f));
    oa.w[1] = f2bf2(fmaxf(acc1A[u][2], 0.f), fmaxf(acc1A[u][3], 0.f));
    ob.w[0] = f2bf2(fmaxf(acc1B[u][0], 0.f), fmaxf(acc1B[u][1], 0.f));
    ob.w[1] = f2bf2(fmaxf(acc1B[u][2], 0.f), fmaxf(acc1B[u][3], 0.f));
    pbA[u] = oa.s; pbB[u] = ob.s;
  }

  floatx4 acc2A[8], acc2B[8];
#pragma unroll
  for (int t = 0; t < 8; t++) {
    floatx4 z2 = *(const floatx4*)&fb[128 + t * 16 + quad * 4];   // folded b2
    acc2A[t] = z2; acc2B[t] = z2;
  }
#pragma unroll
  for (int u = 0; u < 8; u++)
#pragma unroll
    for (int t = 0; t < 8; t++) {
      bf4 a4 = *(const bf4*)&w2f[((u * 8 + t) * 64 + lane) * 4];
      acc2A[t] = mfma16(a4, pbA[u], acc2A[t]);
      acc2B[t] = mfma16(a4, pbB[u], acc2B[t]);
    }

#pragma unroll
  for (int tile = 0; tile < 2; tile++) {
    floatx4* acc2 = tile ? acc2B : acc2A;
    int rowbase = tile ? rowB : rowA;
    float qq = 0.f, pp = 0.f;
#pragma unroll
    for (int t = 0; t < 8; t++)
#pragma unroll
      for (int r = 0; r < 4; r++) {
        float h = acc2[t][r];
        float hp = dpp_xor1(h);
        qq += h * h;
        pp += h * hp;
      }
    qq += __shfl_xor(qq, 16, 64);
    pp += __shfl_xor(pp, 16, 64);
    qq += __shfl_xor(qq, 32, 64);
    pp += __shfl_xor(pp, 32, 64);
    float rr = dpp_xor1(qq);

    if (quad == 0 && !(l15 & 1)) {
      int e = (rowbase + l15) >> 1;
      float n1 = fmaxf(sqrtf(qq), 1e-8f);
      float n2 = fmaxf(sqrtf(rr), 1e-8f);
      float w = (pp / (n1 * n2) + 1.f) * 0.5f;
      ew_out[e] = w;
      atomicAdd(deg + eidx[e], w);
      atomicAdd(cnt + eidx[EE + e], 1);
    }
  }
}

// ---------------- features fp32 -> bf16 ----------------
__global__ __launch_bounds__(256) void fconv_kernel(const float* __restrict__ src,
                                                    unsigned short* __restrict__ dst) {
  size_t i = ((size_t)blockIdx.x * 256 + threadIdx.x) * 8;
  float4 a = *(const float4*)(src + i);
  float4 b = *(const float4*)(src + i + 4);
  union { ushort8 s; unsigned u[4]; } o;
  o.u[0] = f2bf2(a.x, a.y); o.u[1] = f2bf2(a.z, a.w);
  o.u[2] = f2bf2(b.x, b.y); o.u[3] = f2bf2(b.z, b.w);
  *(ushort8*)(dst + i) = o.s;
}

// ---------------- weights: transpose 256x256 chunks, fp32 -> bf16, Cheb fold ----------------
// Chebyshev identity fold: h = x(W0-W2) + Tx1*W1 + (P*Tx1)*(2*W2) -- exact algebra,
// lets prop2 be a pure SpMM (no sub-read, no subtract).
__global__ __launch_bounds__(256) void wconv_kernel(
    const float* __restrict__ cheb_w, const float* __restrict__ cls_w1,
    unsigned short* __restrict__ wtc, unsigned short* __restrict__ clsT)
{
  __shared__ unsigned short tile[64][80];
  int z = blockIdx.z;
  const float* src; const float* src2 = nullptr; float scale = 1.f;
  unsigned short* dst; int ldk;
  if (z < 12) {
    int l = z / 3, c = z % 3;
    src = cheb_w + (size_t)z * 65536;
    if (c == 0) src2 = cheb_w + (size_t)(l * 3 + 2) * 65536;  // W0 - W2
    if (c == 2) scale = 2.f;                                   // 2*W2
    dst = wtc + (size_t)l * 196608 + c * 256;
    ldk = 768;
  } else {
    int c = z - 12;
    src = cls_w1 + (size_t)c * 65536;
    dst = clsT + c * 256;
    ldk = 1024;
  }
  int t = threadIdx.x;
  int k0 = blockIdx.x * 64, n0 = blockIdx.y * 64;
#pragma unroll
  for (int pass = 0; pass < 4; pass++) {
    int kk = pass * 16 + (t >> 4);
    int nl = (t & 15) * 4;
    size_t offe = (size_t)(k0 + kk) * 256 + n0 + nl;
    float4 v = *(const float4*)(src + offe);
    if (src2) {
      float4 v2 = *(const float4*)(src2 + offe);
      v.x -= v2.x; v.y -= v2.y; v.z -= v2.z; v.w -= v2.w;
    } else if (scale != 1.f) {
      v.x *= scale; v.y *= scale; v.z *= scale; v.w *= scale;
    }
    tile[nl + 0][kk] = f2bf(v.x);
    tile[nl + 1][kk] = f2bf(v.y);
    tile[nl + 2][kk] = f2bf(v.z);
    tile[nl + 3][kk] = f2bf(v.w);
  }
  __syncthreads();
  int nl = t >> 2, kc = (t & 3) * 16;
  ushort8 v0 = *(const ushort8*)&tile[nl][kc];
  ushort8 v1 = *(const ushort8*)&tile[nl][kc + 8];
  unsigned short* dp = dst + (size_t)(n0 + nl) * ldk + k0 + kc;
  *(ushort8*)dp = v0;
  *(ushort8*)(dp + 8) = v1;
}

// ---------------- degree histogram: per-block LDS aggregate -> few global atomics ----------------
// Runs BEFORE scan_kernel so scan's tail can consume hist (fused binscan).
__global__ __launch_bounds__(256) void hist_kernel(const int* __restrict__ cnt,
                                                   int* __restrict__ hist) {
  __shared__ int lh[64];
  int tid = threadIdx.x;
  if (tid < 64) lh[tid] = 0;
  __syncthreads();
  int i = blockIdx.x * 256 + tid;
  if (i < NN) {
    int b = (cnt[i] + 3) >> 2; if (b > 63) b = 63;
    atomicAdd(&lh[b], 1);
  }
  __syncthreads();
  if (tid < 64 && lh[tid]) atomicAdd(&hist[tid], lh[tid]);
}

// ---------------- exclusive scan of in-degree counts + fused 64-bin scan tail ----------------
// Tail (lanes 0-63 of wave 0): exclusive-scan the ready global hist -> binbase, zero
// binfill. Removes the separate binscan dispatch.
__global__ __launch_bounds__(1024) void scan_kernel(const int* __restrict__ cnt, int* __restrict__ ptr,
                                                    const int* __restrict__ hist,
                                                    int* __restrict__ binbase, int* __restrict__ binfill) {
  __shared__ int sums[1024];
  int tid = threadIdx.x;
  const int n = NN;
  const int chunk = (n + 1023) / 1024;
  int base = tid * chunk;
  int s = 0;
  for (int i = 0; i < chunk; i++) {
    int idx = base + i;
    if (idx < n) s += (cnt[idx] + 3) & ~3;
  }
  sums[tid] = s;
  __syncthreads();
  for (int off = 1; off < 1024; off <<= 1) {
    int v = (tid >= off) ? sums[tid - off] : 0;
    __syncthreads();
    sums[tid] += v;
    __syncthreads();
  }
  int run = (tid == 0) ? 0 : sums[tid - 1];
  for (int i = 0; i < chunk; i++) {
    int idx = base + i;
    if (idx < n) { ptr[idx] = run; run += (cnt[idx] + 3) & ~3; }
  }
  if (tid == 1023) ptr[n] = run;
  if (tid < 64) {
    int v = hist[tid];
    int x = v;
#pragma unroll
    for (int off = 1; off < 64; off <<= 1) {
      int y = __shfl_up(x, off, 64);
      if (tid >= off) x += y;
    }
    binbase[tid] = x - v;
    binfill[tid] = 0;
  }
}

// ---------------- fused perm + CSR fill (independent workloads, one dispatch) ----------------
// Blocks [0,PB): degree-binned node permutation (block-aggregated atomics, round-6).
// Blocks [PB,..): CSR fill with packed (idx<<16 | bf16 val) slots (round-12).
#define PB ((NN + 255) / 256)
__global__ __launch_bounds__(256) void permfill_kernel(
    const int* __restrict__ cnt, const int* __restrict__ binbase,
    int* __restrict__ binfill, int* __restrict__ perm,
    const int* __restrict__ eidx, const float* __restrict__ ew,
    const float* __restrict__ deg, const int* __restrict__ ptr,
    int* __restrict__ fill, unsigned* __restrict__ epack)
{
  int tid = threadIdx.x;
  if (blockIdx.x < PB) {
    __shared__ int lh[64], lbase[64];
    if (tid < 64) lh[tid] = 0;
    __syncthreads();
    int i = blockIdx.x * 256 + tid;
    int b = 0, local = 0;
    bool valid = (i < NN);
    if (valid) {
      b = (cnt[i] + 3) >> 2; if (b > 63) b = 63;
      local = atomicAdd(&lh[b], 1);        // LDS atomic: cheap
    }
    __syncthreads();
    if (tid < 64 && lh[tid]) lbase[tid] = atomicAdd(&binfill[tid], lh[tid]);  // 1/block/bin
    __syncthreads();
    if (valid) perm[binbase[b] + lbase[b] + local] = i;
  } else {
    int e = (blockIdx.x - PB) * 256 + tid;
    if (e < EE) {
      int r = eidx[e], c = eidx[EE + e];
      float dr = deg[r], dc = deg[c];
      float ir = dr > 0.f ? 1.f / sqrtf(fmaxf(dr, 1e-30f)) : 0.f;
      float ic = dc > 0.f ? 1.f / sqrtf(fmaxf(dc, 1e-30f)) : 0.f;
      float nv = -ir * ew[e] * ic;
      int pos = ptr[c] + atomicAdd(&fill[c], 1);
      epack[pos] = ((unsigned)r << 16) | (unsigned short)f2bf(nv);
    }
  }
}

// ---------------- sparse prop (bf16, 4-way XCD slice, degree-binned, depth-2) ----------------
// ROUND-12 PROVEN (623.7 us): 64-ch slices -> 128 B gather segments (full L2 line;
// round-11's 64 B segments wasted half of every fetched line, -52 us). Packed epack
// (4 B/edge), per-XCD footprint ~3.4 MB.
__global__ __launch_bounds__(256) void prop_kernel(
    const unsigned short* __restrict__ x, int ldx,
    const unsigned* __restrict__ epack,
    const int* __restrict__ ptr, const int* __restrict__ perm,
    unsigned short* __restrict__ y, int ldy)
{
  int sliceid = blockIdx.x & 7;
  int colslice = sliceid >> 1;                       // 0..3  (64 ch = 128 B)
  int chunk = (blockIdx.x >> 3) * 2 + (sliceid & 1); // 0..625
  int ci = chunk * 32 + (threadIdx.x >> 3);
  if (ci >= NN) return;
  int c = perm[ci];
  int d = colslice * 64 + (threadIdx.x & 7) * 8;
  int p0 = ptr[c], p1 = ptr[c + 1];
  float a[8] = {0.f, 0.f, 0.f, 0.f, 0.f, 0.f, 0.f, 0.f};

#define PLOAD(P, PK, V0, V1, V2, V3)                                    \
  do {                                                                  \
    PK = *(const uint4*)(epack + (P));                                  \
    V0 = *(const ushort8*)(x + (size_t)(PK.x >> 16) * ldx + d);         \
    V1 = *(const ushort8*)(x + (size_t)(PK.y >> 16) * ldx + d);         \
    V2 = *(const ushort8*)(x + (size_t)(PK.z >> 16) * ldx + d);         \
    V3 = *(const ushort8*)(x + (size_t)(PK.w >> 16) * ldx + d);         \
  } while (0)

#define PACC(PK, V0, V1, V2, V3)                                        \
  do {                                                                  \
    float w0 = bf2f((unsigned short)(PK.x & 0xffffu));                  \
    float w1 = bf2f((unsigned short)(PK.y & 0xffffu));                  \
    float w2 = bf2f((unsigned short)(PK.z & 0xffffu));                  \
    float w3 = bf2f((unsigned short)(PK.w & 0xffffu));                  \
    _Pragma("unroll")                                                   \
    for (int j = 0; j < 8; j++)                                         \
      a[j] += w0 * bf2f(V0[j]) + w1 * bf2f(V1[j]) +                     \
              w2 * bf2f(V2[j]) + w3 * bf2f(V3[j]);                      \
  } while (0)

  if (p0 < p1) {
    int n4 = (p1 - p0) >> 2;
    uint4 kA, kB;
    ushort8 vA0, vA1, vA2, vA3, vB0, vB1, vB2, vB3;
    PLOAD(p0, kA, vA0, vA1, vA2, vA3);
    if (n4 == 1) {
      PACC(kA, vA0, vA1, vA2, vA3);
    } else {
      PLOAD(p0 + 4, kB, vB0, vB1, vB2, vB3);
      int p = p0 + 8;
      if (n4 & 1) {                       // consume one to make remaining even
        PACC(kA, vA0, vA1, vA2, vA3);
        PLOAD(p, kA, vA0, vA1, vA2, vA3);
        p += 4;
      }
      for (; p < p1; p += 8) {
        PACC(kA, vA0, vA1, vA2, vA3);
        PLOAD(p, kA, vA0, vA1, vA2, vA3);
        PACC(kB, vB0, vB1, vB2, vB3);
        PLOAD(p + 4, kB, vB0, vB1, vB2, vB3);
      }
      PACC(kA, vA0, vA1, vA2, vA3);
      PACC(kB, vB0, vB1, vB2, vB3);
    }
  }
#undef PLOAD
#undef PACC

  union { ushort8 s; unsigned u[4]; } o;
#pragma unroll
  for (int j = 0; j < 8; j += 2)
    o.u[j >> 1] = f2bf2(a[j], a[j + 1]);
  *(ushort8*)(y + (size_t)c * ldy + d) = o.s;
}

// ---------------- bf16 MFMA GEMM: C = post( sum_c A_c @ B_c ) ----------------
// launch_bounds(256,4): 12 KB LDS -> 4 blocks/CU. XCD-swizzled blockIdx.x (T1).
__global__ __launch_bounds__(256, 4) void mgemm_kernel(
    const unsigned short* A0, const unsigned short* A1,
    const unsigned short* A2, const unsigned short* A3,
    int l0, int l1, int l2, int l3, int nchunks,
    const unsigned short* __restrict__ BT, int ldbt,
    unsigned short* __restrict__ Cb, float* __restrict__ Cf, int ldc, int M,
    const float* __restrict__ bias, const float* __restrict__ bng,
    const float* __restrict__ bnb)
{
  __shared__ short As[4 * 64 * 8];
  __shared__ short Bs[4 * 128 * 8];
  int tid = threadIdx.x;
  int lane = tid & 63;
  int wv = tid >> 6;
  int l15 = lane & 15, quad = lane >> 4;
  int wr = wv >> 1, wc = wv & 1;
  int bidx = xcd_swizzle(blockIdx.x, gridDim.x);
  int m0 = bidx * 64, n0 = blockIdx.y * 128;

  const unsigned short* Ap[4] = {A0, A1, A2, A3};
  int Al[4] = {l0, l1, l2, l3};

  int arow = tid & 63, ac = tid >> 6;
  int brow = tid & 127, bc = tid >> 7;

  floatx4 acc[2][4];
#pragma unroll
  for (int mi = 0; mi < 2; mi++)
#pragma unroll
    for (int nj = 0; nj < 4; nj++) acc[mi][nj] = (floatx4){0.f, 0.f, 0.f, 0.f};

  for (int c = 0; c < nchunks; c++) {
    const unsigned short* Abase = Ap[c] + (size_t)(m0 + arow) * Al[c] + ac * 8;
    const unsigned short* Bbase = BT + (size_t)(n0 + brow) * ldbt + c * 256 + bc * 8;
#pragma unroll 1
    for (int kb = 0; kb < 256; kb += 32) {
      __syncthreads();
      gl_lds16(Abase + kb, &As[tid * 8]);
      gl_lds16(Bbase + kb, &Bs[tid * 8]);
      gl_lds16(Bbase + 16 + kb, &Bs[(tid + 256) * 8]);
      __syncthreads();
      short8 af[2], bfv[4];
#pragma unroll
      for (int mi = 0; mi < 2; mi++)
        af[mi] = *(const short8*)&As[(quad * 64 + wr * 32 + mi * 16 + l15) * 8];
#pragma unroll
      for (int nj = 0; nj < 4; nj++)
        bfv[nj] = *(const short8*)&Bs[(quad * 128 + wc * 64 + nj * 16 + l15) * 8];
#pragma unroll
      for (int nj = 0; nj < 4; nj++)
#pragma unroll
        for (int mi = 0; mi < 2; mi++)
          acc[mi][nj] = __builtin_amdgcn_mfma_f32_16x16x32_bf16(af[mi], bfv[nj], acc[mi][nj], 0, 0, 0);
    }
  }

  if (Cb) {
#pragma unroll
    for (int mi = 0; mi < 2; mi++)
#pragma unroll
      for (int r = 0; r < 4; r++) {
        int row = m0 + wr * 32 + mi * 16 + quad * 4 + r;
        if (row < M) {
#pragma unroll
          for (int nj = 0; nj < 4; nj++) {
            int col = n0 + wc * 64 + nj * 16 + l15;
            Cb[(size_t)row * ldc + col] = (unsigned short)f2bf(fmaxf(acc[mi][nj][r], 0.f));
          }
        }
      }
  } else {
    float bs[4], g[4], bb[4];
#pragma unroll
    for (int nj = 0; nj < 4; nj++) {
      int col = n0 + wc * 64 + nj * 16 + l15;
      bs[nj] = bias[col]; g[nj] = bng[col] * RSBN; bb[nj] = bnb[col];
    }
#pragma unroll
    for (int mi = 0; mi < 2; mi++)
#pragma unroll
      for (int r = 0; r < 4; r++) {
        int row = m0 + wr * 32 + mi * 16 + quad * 4 + r;
        if (row < M) {
#pragma unroll
          for (int nj = 0; nj < 4; nj++) {
            int col = n0 + wc * 64 + nj * 16 + l15;
            float v = fmaxf(acc[mi][nj][r] + bs[nj], 0.f) * g[nj] + bb[nj];
            Cf[(size_t)row * ldc + col] = v;
          }
        }
      }
  }
}

// ---------------- final 256x2 matvec per node ----------------
__global__ __launch_bounds__(256) void logit_kernel(
    const float* __restrict__ z, const float* __restrict__ w2,
    const float* __restrict__ b2, float* __restrict__ out)
{
  int node = blockIdx.x * 4 + (threadIdx.x >> 6);
  if (node >= NN) return;
  int lane = threadIdx.x & 63;
  int k = lane * 4;
  float4 zv = *(const float4*)(z + (size_t)node * 256 + k);
  float4 wa = *(const float4*)(w2 + k * 2);
  float4 wb = *(const float4*)(w2 + k * 2 + 4);
  float a0 = zv.x * wa.x + zv.y * wa.z + zv.z * wb.x + zv.w * wb.z;
  float a1 = zv.x * wa.y + zv.y * wa.w + zv.z * wb.y + zv.w * wb.w;
#pragma unroll
  for (int m = 32; m >= 1; m >>= 1) {
    a0 += __shfl_xor(a0, m, 64);
    a1 += __shfl_xor(a1, m, 64);
  }
  if (lane == 0) {
    out[(size_t)node * 2]     = a0 + b2[0];
    out[(size_t)node * 2 + 1] = a1 + b2[1];
  }
}

extern "C" void kernel_launch(void* const* d_in, const int* in_sizes, int n_in,
                              void* d_out, int out_size, void* d_ws, size_t ws_size,
                              hipStream_t stream) {
  const float* features = (const float*)d_in[0];
  const int*   eidx     = (const int*)d_in[1];
  const float* xin      = (const float*)d_in[2];
  const float* cheb_w   = (const float*)d_in[3];
  const float* en_w1    = (const float*)d_in[4];
  const float* en_b1    = (const float*)d_in[5];
  const float* en_g1    = (const float*)d_in[6];
  const float* en_be1   = (const float*)d_in[7];
  const float* en_w2    = (const float*)d_in[8];
  const float* en_b2    = (const float*)d_in[9];
  const float* cls_w1   = (const float*)d_in[10];
  const float* cls_b1   = (const float*)d_in[11];
  const float* cls_g    = (const float*)d_in[12];
  const float* cls_b    = (const float*)d_in[13];
  const float* cls_w2   = (const float*)d_in[14];
  const float* cls_b2   = (const float*)d_in[15];
  float* out = (float*)d_out;

  char* ws = (char*)d_ws;
  size_t off = 0;
  auto alloc = [&](size_t bytes) -> void* {
    void* p = ws + off;
    off += (bytes + 255) & ~(size_t)255;
    return p;
  };
  const int CSRN = EE + 4 * NN;   // padded CSR capacity
  float* deg  = (float*)alloc((size_t)NN * 4);
  int*   cnt  = (int*)  alloc((size_t)NN * 4);
  int*   fil  = (int*)  alloc((size_t)NN * 4);
  int*   hist = (int*)  alloc(64 * 4);
  unsigned* epack = (unsigned*)alloc((size_t)CSRN * 4);
  size_t zero_len = off;                       // deg+cnt+fil+hist+epack zeroed
  int*   ptr  = (int*)  alloc((size_t)(NN + 1) * 4);
  int*   perm = (int*)  alloc((size_t)NN * 4);
  int*   binbase = (int*)alloc(64 * 4);
  int*   binfill = (int*)alloc(64 * 4);
  unsigned short* featb = (unsigned short*)alloc((size_t)NN * 256 * 2);
  unsigned short* Tx1   = (unsigned short*)alloc((size_t)NN * 256 * 2);
  unsigned short* Tx2   = (unsigned short*)alloc((size_t)NN * 256 * 2);
  unsigned short* jk    = (unsigned short*)alloc((size_t)NN * 1024 * 2);
  float* zbuf = (float*)alloc((size_t)NN * 256 * 4);
  unsigned short* wtc   = (unsigned short*)alloc((size_t)4 * 196608 * 2);
  unsigned short* clsT  = (unsigned short*)alloc((size_t)256 * 1024 * 2);
  unsigned short* ewf   = (unsigned short*)alloc((size_t)20992 * 2);
  alloc(262144);   // overread pad for GEMM tail blocks

  float* ew = out + (size_t)NN * 2;   // edge-weight output doubles as scratch

  hipMemsetAsync(deg, 0, zero_len, stream);

  ewconv_kernel<<<1, 256, 0, stream>>>(en_w1, en_w2, en_g1, en_be1, en_b1, en_b2, ewf);
  edge_kernel<<<3125, 512, 0, stream>>>(xin, eidx, ewf, ew, deg, cnt);
  fconv_kernel<<<2500, 256, 0, stream>>>(features, featb);
  wconv_kernel<<<dim3(4, 4, 16), 256, 0, stream>>>(cheb_w, cls_w1, wtc, clsT);
  hist_kernel<<<(NN + 255) / 256, 256, 0, stream>>>(cnt, hist);
  scan_kernel<<<1, 1024, 0, stream>>>(cnt, ptr, hist, binbase, binfill);
  permfill_kernel<<<PB + (EE + 255) / 256, 256, 0, stream>>>(
      cnt, binbase, binfill, perm, eidx, ew, deg, ptr, fil, epack);

  dim3 ggrid(313, 2);
  for (int i = 0; i < 4; i++) {
    const unsigned short* x = (i == 0) ? featb : (jk + (size_t)(i - 1) * 256);
    int ldx = (i == 0) ? 256 : 1024;
    prop_kernel<<<2504, 256, 0, stream>>>(x, ldx, epack, ptr, perm, Tx1, 256);
    prop_kernel<<<2504, 256, 0, stream>>>(Tx1, 256, epack, ptr, perm, Tx2, 256);
    mgemm_kernel<<<ggrid, 256, 0, stream>>>(x, Tx1, Tx2, nullptr, ldx, 256, 256, 0, 3,
                                            wtc + (size_t)i * 196608, 768,
                                            jk + (size_t)i * 256, nullptr, 1024, NN,
                                            nullptr, nullptr, nullptr);
  }

  mgemm_kernel<<<ggrid, 256, 0, stream>>>(jk, jk + 256, jk + 512, jk + 768,
                                          1024, 1024, 1024, 1024, 4, clsT, 1024,
                                          nullptr, zbuf, 256, NN,
                                          cls_b1, cls_g, cls_b);
  logit_kernel<<<NN / 4, 256, 0, stream>>>(zbuf, cls_w2, cls_b2, out);
}

// Round 15
// 611.352 us; speedup vs baseline: 1.1289x; 1.0154x over previous
//
#include <hip/hip_runtime.h>
#include <hip/hip_bf16.h>

#define NN 20000
#define EE 400000
#define RSBN 0.9999950000374997f   // 1/sqrt(1+1e-5)

typedef __attribute__((ext_vector_type(8))) short short8;
typedef __attribute__((ext_vector_type(8))) unsigned short ushort8;
typedef __attribute__((ext_vector_type(4))) short bf4;
typedef __attribute__((ext_vector_type(4))) float floatx4;

__device__ __forceinline__ short f2bf(float f) {
  union { float f; unsigned u; } v; v.f = f;
  unsigned r = v.u + 0x7fffu + ((v.u >> 16) & 1u);   // RNE
  return (short)(r >> 16);
}
__device__ __forceinline__ unsigned f2bf2(float x, float y) {   // packed cvt
  union { __hip_bfloat162 h; unsigned u; } v;
  v.h = __float22bfloat162_rn(make_float2(x, y));
  return v.u;
}
__device__ __forceinline__ float bf2f(unsigned short u) {
  union { unsigned u; float f; } v; v.u = ((unsigned)u) << 16;
  return v.f;
}
__device__ __forceinline__ void gl_lds16(const void* g, void* l) {
  __builtin_amdgcn_global_load_lds(
      (const __attribute__((address_space(1))) unsigned*)g,
      (__attribute__((address_space(3))) unsigned*)l, 16, 0, 0);
}

__device__ __forceinline__ floatx4 mfma16(bf4 a, bf4 b, floatx4 c) {
#if __has_builtin(__builtin_amdgcn_mfma_f32_16x16x16bf16_1k)
  return __builtin_amdgcn_mfma_f32_16x16x16bf16_1k(a, b, c, 0, 0, 0);
#else
  floatx4 d;
  asm volatile("v_mfma_f32_16x16x16_bf16 %0, %1, %2, %3"
               : "=&v"(d) : "v"(a), "v"(b), "v"(c));
  return d;
#endif
}

// lane^1 exchange via DPP quad_perm(1,0,3,2): full-rate VALU, no DS-pipe traffic
__device__ __forceinline__ float dpp_xor1(float x) {
  union { float f; int i; } a, b;
  a.f = x;
  b.i = __builtin_amdgcn_update_dpp(0, a.i, 0xB1, 0xF, 0xF, false);
  return b.f;
}

// bijective XCD-aware remap of a 1D block index (m204 formula)
__device__ __forceinline__ int xcd_swizzle(int bid, int nwg) {
  int q = nwg >> 3, r = nwg & 7;
  int x = bid & 7, o = bid >> 3;
  return (x < r ? x * (q + 1) : r * (q + 1) + (x - r) * q) + o;
}

// ---------------- edge-parser weights -> fragment-layout bf16 + folded consts ----------------
__global__ __launch_bounds__(256) void ewconv_kernel(
    const float* __restrict__ w1, const float* __restrict__ w2,
    const float* __restrict__ g1, const float* __restrict__ be1,
    const float* __restrict__ b1, const float* __restrict__ b2,
    unsigned short* __restrict__ ewf)
{
  int tid = threadIdx.x;
#pragma unroll
  for (int i = 0; i < 16; i++) {
    int idx = i * 256 + tid;
    int k = idx >> 7, n = idx & 127;
    int pos = ((n >> 4) * 64 + (k >> 3) * 16 + (n & 15)) * 8 + (k & 7);
    ewf[pos] = f2bf(w1[idx]);
  }
#pragma unroll
  for (int i = 0; i < 64; i++) {
    int idx = i * 256 + tid;
    int k = idx >> 7, n = idx & 127;
    int u = k >> 4, q = (k >> 2) & 3, j = k & 3;
    int t = n >> 4, l = n & 15;
    int pos = (((u * 8 + t) * 4 + q) * 16 + l) * 4 + j;
    ewf[4096 + pos] = f2bf(w2[idx] * g1[k] * RSBN);   // BN scale folded
  }
  float* fb = (float*)(ewf + 20480);
  if (tid < 128) {
    fb[tid] = b1[tid];
    float acc = b2[tid];
    for (int k = 0; k < 128; k++) acc += be1[k] * w2[k * 128 + tid] * g1[k] * RSBN;
    fb[128 + tid] = acc;
  }
}

// ---------------- edge parser + edge weight (swapped MFMA, 2 tiles/wave) ----------------
// 2-tile version (round 7, counter-verified ~73.5 us). launch_bounds(512,4) = 128 VGPR
// cap (round-2 spill lesson: past the cap, accumulators spill -> 25x scratch traffic).
__global__ __launch_bounds__(512, 4) void edge_kernel(
    const float* __restrict__ xin, const int* __restrict__ eidx,
    const unsigned short* __restrict__ ewf,
    float* __restrict__ ew_out,
    float* __restrict__ deg, int* __restrict__ cnt)
{
  __shared__ short wbuf[20992];

  int tid = threadIdx.x;
  int lane = tid & 63;
  int wv = tid >> 6;
  int l15 = lane & 15;
  int quad = lane >> 4;

#pragma unroll
  for (int i = 0; i < 5; i++)
    gl_lds16(ewf + (i * 512 + tid) * 8, &wbuf[(i * 512 + tid) * 8]);
  if (tid < 64)
    gl_lds16(ewf + (2560 + tid) * 8, &wbuf[(2560 + tid) * 8]);

  const short* w1f = wbuf;
  const short* w2f = wbuf + 4096;

  int rowA = blockIdx.x * 256 + wv * 16;
  int rowB = rowA + 128;

  short8 afA, afB;
  {
    const float* xpA = xin + (size_t)(rowA + l15) * 32 + quad * 8;
    const float* xpB = xin + (size_t)(rowB + l15) * 32 + quad * 8;
    float4 a0 = *(const float4*)xpA;
    float4 a1 = *(const float4*)(xpA + 4);
    float4 b0 = *(const float4*)xpB;
    float4 b1v = *(const float4*)(xpB + 4);
    union { short8 s; unsigned u[4]; } a, b;
    a.u[0] = f2bf2(a0.x, a0.y); a.u[1] = f2bf2(a0.z, a0.w);
    a.u[2] = f2bf2(a1.x, a1.y); a.u[3] = f2bf2(a1.z, a1.w);
    b.u[0] = f2bf2(b0.x, b0.y); b.u[1] = f2bf2(b0.z, b0.w);
    b.u[2] = f2bf2(b1v.x, b1v.y); b.u[3] = f2bf2(b1v.z, b1v.w);
    afA = a.s; afB = b.s;
  }

  __syncthreads();

  const float* fb = (const float*)(wbuf + 20480);

  floatx4 acc1A[8], acc1B[8];
#pragma unroll
  for (int t = 0; t < 8; t++) {
    floatx4 z = *(const floatx4*)&fb[t * 16 + quad * 4];   // b1 rows (tile-independent)
    short8 w1v = *(const short8*)&w1f[(t * 64 + lane) * 8];
    acc1A[t] = __builtin_amdgcn_mfma_f32_16x16x32_bf16(w1v, afA, z, 0, 0, 0);
    acc1B[t] = __builtin_amdgcn_mfma_f32_16x16x32_bf16(w1v, afB, z, 0, 0, 0);
  }

  bf4 pbA[8], pbB[8];
#pragma unroll
  for (int u = 0; u < 8; u++) {
    union { bf4 s; unsigned w[2]; } oa, ob;
    oa.w[0] = f2bf2(fmaxf(acc1A[u][0], 0.f), fmaxf(acc1A[u][1], 0.f));
    oa.w[1] = f2bf2(fmaxf(acc1A[u][2], 0.f), fmaxf(acc1A[u][3], 0.f));
    ob.w[0] = f2bf2(fmaxf(acc1B[u][0], 0.f), fmaxf(acc1B[u][1], 0.f));
    ob.w[1] = f2bf2(fmaxf(acc1B[u][2], 0.f), fmaxf(acc1B[u][3], 0.f));
    pbA[u] = oa.s; pbB[u] = ob.s;
  }

  floatx4 acc2A[8], acc2B[8];
#pragma unroll
  for (int t = 0; t < 8; t++) {
    floatx4 z2 = *(const floatx4*)&fb[128 + t * 16 + quad * 4];   // folded b2
    acc2A[t] = z2; acc2B[t] = z2;
  }
#pragma unroll
  for (int u = 0; u < 8; u++)
#pragma unroll
    for (int t = 0; t < 8; t++) {
      bf4 a4 = *(const bf4*)&w2f[((u * 8 + t) * 64 + lane) * 4];
      acc2A[t] = mfma16(a4, pbA[u], acc2A[t]);
      acc2B[t] = mfma16(a4, pbB[u], acc2B[t]);
    }

#pragma unroll
  for (int tile = 0; tile < 2; tile++) {
    floatx4* acc2 = tile ? acc2B : acc2A;
    int rowbase = tile ? rowB : rowA;
    float qq = 0.f, pp = 0.f;
#pragma unroll
    for (int t = 0; t < 8; t++)
#pragma unroll
      for (int r = 0; r < 4; r++) {
        float h = acc2[t][r];
        float hp = dpp_xor1(h);
        qq += h * h;
        pp += h * hp;
      }
    qq += __shfl_xor(qq, 16, 64);
    pp += __shfl_xor(pp, 16, 64);
    qq += __shfl_xor(qq, 32, 64);
    pp += __shfl_xor(pp, 32, 64);
    float rr = dpp_xor1(qq);

    if (quad == 0 && !(l15 & 1)) {
      int e = (rowbase + l15) >> 1;
      float n1 = fmaxf(sqrtf(qq), 1e-8f);
      float n2 = fmaxf(sqrtf(rr), 1e-8f);
      float w = (pp / (n1 * n2) + 1.f) * 0.5f;
      ew_out[e] = w;
      atomicAdd(deg + eidx[e], w);
      atomicAdd(cnt + eidx[EE + e], 1);
    }
  }
}

// ---------------- features fp32 -> bf16 ----------------
__global__ __launch_bounds__(256) void fconv_kernel(const float* __restrict__ src,
                                                    unsigned short* __restrict__ dst) {
  size_t i = ((size_t)blockIdx.x * 256 + threadIdx.x) * 8;
  float4 a = *(const float4*)(src + i);
  float4 b = *(const float4*)(src + i + 4);
  union { ushort8 s; unsigned u[4]; } o;
  o.u[0] = f2bf2(a.x, a.y); o.u[1] = f2bf2(a.z, a.w);
  o.u[2] = f2bf2(b.x, b.y); o.u[3] = f2bf2(b.z, b.w);
  *(ushort8*)(dst + i) = o.s;
}

// ---------------- weights: transpose 256x256 chunks, fp32 -> bf16, Cheb fold ----------------
// Chebyshev identity fold: h = x(W0-W2) + Tx1*W1 + (P*Tx1)*(2*W2) -- exact algebra,
// lets prop2 be a pure SpMM (no sub-read, no subtract).
__global__ __launch_bounds__(256) void wconv_kernel(
    const float* __restrict__ cheb_w, const float* __restrict__ cls_w1,
    unsigned short* __restrict__ wtc, unsigned short* __restrict__ clsT)
{
  __shared__ unsigned short tile[64][80];
  int z = blockIdx.z;
  const float* src; const float* src2 = nullptr; float scale = 1.f;
  unsigned short* dst; int ldk;
  if (z < 12) {
    int l = z / 3, c = z % 3;
    src = cheb_w + (size_t)z * 65536;
    if (c == 0) src2 = cheb_w + (size_t)(l * 3 + 2) * 65536;  // W0 - W2
    if (c == 2) scale = 2.f;                                   // 2*W2
    dst = wtc + (size_t)l * 196608 + c * 256;
    ldk = 768;
  } else {
    int c = z - 12;
    src = cls_w1 + (size_t)c * 65536;
    dst = clsT + c * 256;
    ldk = 1024;
  }
  int t = threadIdx.x;
  int k0 = blockIdx.x * 64, n0 = blockIdx.y * 64;
#pragma unroll
  for (int pass = 0; pass < 4; pass++) {
    int kk = pass * 16 + (t >> 4);
    int nl = (t & 15) * 4;
    size_t offe = (size_t)(k0 + kk) * 256 + n0 + nl;
    float4 v = *(const float4*)(src + offe);
    if (src2) {
      float4 v2 = *(const float4*)(src2 + offe);
      v.x -= v2.x; v.y -= v2.y; v.z -= v2.z; v.w -= v2.w;
    } else if (scale != 1.f) {
      v.x *= scale; v.y *= scale; v.z *= scale; v.w *= scale;
    }
    tile[nl + 0][kk] = f2bf(v.x);
    tile[nl + 1][kk] = f2bf(v.y);
    tile[nl + 2][kk] = f2bf(v.z);
    tile[nl + 3][kk] = f2bf(v.w);
  }
  __syncthreads();
  int nl = t >> 2, kc = (t & 3) * 16;
  ushort8 v0 = *(const ushort8*)&tile[nl][kc];
  ushort8 v1 = *(const ushort8*)&tile[nl][kc + 8];
  unsigned short* dp = dst + (size_t)(n0 + nl) * ldk + k0 + kc;
  *(ushort8*)dp = v0;
  *(ushort8*)(dp + 8) = v1;
}

// ---------------- degree histogram: per-block LDS aggregate -> few global atomics ----------------
// Runs BEFORE scan_kernel so scan's tail can consume hist (fused binscan).
__global__ __launch_bounds__(256) void hist_kernel(const int* __restrict__ cnt,
                                                   int* __restrict__ hist) {
  __shared__ int lh[64];
  int tid = threadIdx.x;
  if (tid < 64) lh[tid] = 0;
  __syncthreads();
  int i = blockIdx.x * 256 + tid;
  if (i < NN) {
    int b = (cnt[i] + 3) >> 2; if (b > 63) b = 63;
    atomicAdd(&lh[b], 1);
  }
  __syncthreads();
  if (tid < 64 && lh[tid]) atomicAdd(&hist[tid], lh[tid]);
}

// ---------------- exclusive scan of in-degree counts + fused 64-bin scan tail ----------------
__global__ __launch_bounds__(1024) void scan_kernel(const int* __restrict__ cnt, int* __restrict__ ptr,
                                                    const int* __restrict__ hist,
                                                    int* __restrict__ binbase, int* __restrict__ binfill) {
  __shared__ int sums[1024];
  int tid = threadIdx.x;
  const int n = NN;
  const int chunk = (n + 1023) / 1024;
  int base = tid * chunk;
  int s = 0;
  for (int i = 0; i < chunk; i++) {
    int idx = base + i;
    if (idx < n) s += (cnt[idx] + 3) & ~3;
  }
  sums[tid] = s;
  __syncthreads();
  for (int off = 1; off < 1024; off <<= 1) {
    int v = (tid >= off) ? sums[tid - off] : 0;
    __syncthreads();
    sums[tid] += v;
    __syncthreads();
  }
  int run = (tid == 0) ? 0 : sums[tid - 1];
  for (int i = 0; i < chunk; i++) {
    int idx = base + i;
    if (idx < n) { ptr[idx] = run; run += (cnt[idx] + 3) & ~3; }
  }
  if (tid == 1023) ptr[n] = run;
  if (tid < 64) {
    int v = hist[tid];
    int x = v;
#pragma unroll
    for (int off = 1; off < 64; off <<= 1) {
      int y = __shfl_up(x, off, 64);
      if (tid >= off) x += y;
    }
    binbase[tid] = x - v;
    binfill[tid] = 0;
  }
}

// ---------------- fused perm + CSR fill (independent workloads, one dispatch) ----------------
#define PB ((NN + 255) / 256)
__global__ __launch_bounds__(256) void permfill_kernel(
    const int* __restrict__ cnt, const int* __restrict__ binbase,
    int* __restrict__ binfill, int* __restrict__ perm,
    const int* __restrict__ eidx, const float* __restrict__ ew,
    const float* __restrict__ deg, const int* __restrict__ ptr,
    int* __restrict__ fill, unsigned* __restrict__ epack)
{
  int tid = threadIdx.x;
  if (blockIdx.x < PB) {
    __shared__ int lh[64], lbase[64];
    if (tid < 64) lh[tid] = 0;
    __syncthreads();
    int i = blockIdx.x * 256 + tid;
    int b = 0, local = 0;
    bool valid = (i < NN);
    if (valid) {
      b = (cnt[i] + 3) >> 2; if (b > 63) b = 63;
      local = atomicAdd(&lh[b], 1);        // LDS atomic: cheap
    }
    __syncthreads();
    if (tid < 64 && lh[tid]) lbase[tid] = atomicAdd(&binfill[tid], lh[tid]);  // 1/block/bin
    __syncthreads();
    if (valid) perm[binbase[b] + lbase[b] + local] = i;
  } else {
    int e = (blockIdx.x - PB) * 256 + tid;
    if (e < EE) {
      int r = eidx[e], c = eidx[EE + e];
      float dr = deg[r], dc = deg[c];
      float ir = dr > 0.f ? 1.f / sqrtf(fmaxf(dr, 1e-30f)) : 0.f;
      float ic = dc > 0.f ? 1.f / sqrtf(fmaxf(dc, 1e-30f)) : 0.f;
      float nv = -ir * ew[e] * ic;
      int pos = ptr[c] + atomicAdd(&fill[c], 1);
      epack[pos] = ((unsigned)r << 16) | (unsigned short)f2bf(nv);
    }
  }
}

// ---------------- sparse prop (bf16, 4-way XCD slice, degree-binned, depth-2) ----------------
// ROUND-12 PROVEN (623.7 us): 64-ch slices -> 128 B gather segments (full L2 line;
// round-11's 64 B segments wasted half of every fetched line, -52 us). Packed epack
// (4 B/edge), per-XCD footprint ~3.4 MB.
__global__ __launch_bounds__(256) void prop_kernel(
    const unsigned short* __restrict__ x, int ldx,
    const unsigned* __restrict__ epack,
    const int* __restrict__ ptr, const int* __restrict__ perm,
    unsigned short* __restrict__ y, int ldy)
{
  int sliceid = blockIdx.x & 7;
  int colslice = sliceid >> 1;                       // 0..3  (64 ch = 128 B)
  int chunk = (blockIdx.x >> 3) * 2 + (sliceid & 1); // 0..625
  int ci = chunk * 32 + (threadIdx.x >> 3);
  if (ci >= NN) return;
  int c = perm[ci];
  int d = colslice * 64 + (threadIdx.x & 7) * 8;
  int p0 = ptr[c], p1 = ptr[c + 1];
  float a[8] = {0.f, 0.f, 0.f, 0.f, 0.f, 0.f, 0.f, 0.f};

#define PLOAD(P, PK, V0, V1, V2, V3)                                    \
  do {                                                                  \
    PK = *(const uint4*)(epack + (P));                                  \
    V0 = *(const ushort8*)(x + (size_t)(PK.x >> 16) * ldx + d);         \
    V1 = *(const ushort8*)(x + (size_t)(PK.y >> 16) * ldx + d);         \
    V2 = *(const ushort8*)(x + (size_t)(PK.z >> 16) * ldx + d);         \
    V3 = *(const ushort8*)(x + (size_t)(PK.w >> 16) * ldx + d);         \
  } while (0)

#define PACC(PK, V0, V1, V2, V3)                                        \
  do {                                                                  \
    float w0 = bf2f((unsigned short)(PK.x & 0xffffu));                  \
    float w1 = bf2f((unsigned short)(PK.y & 0xffffu));                  \
    float w2 = bf2f((unsigned short)(PK.z & 0xffffu));                  \
    float w3 = bf2f((unsigned short)(PK.w & 0xffffu));                  \
    _Pragma("unroll")                                                   \
    for (int j = 0; j < 8; j++)                                         \
      a[j] += w0 * bf2f(V0[j]) + w1 * bf2f(V1[j]) +                     \
              w2 * bf2f(V2[j]) + w3 * bf2f(V3[j]);                      \
  } while (0)

  if (p0 < p1) {
    int n4 = (p1 - p0) >> 2;
    uint4 kA, kB;
    ushort8 vA0, vA1, vA2, vA3, vB0, vB1, vB2, vB3;
    PLOAD(p0, kA, vA0, vA1, vA2, vA3);
    if (n4 == 1) {
      PACC(kA, vA0, vA1, vA2, vA3);
    } else {
      PLOAD(p0 + 4, kB, vB0, vB1, vB2, vB3);
      int p = p0 + 8;
      if (n4 & 1) {                       // consume one to make remaining even
        PACC(kA, vA0, vA1, vA2, vA3);
        PLOAD(p, kA, vA0, vA1, vA2, vA3);
        p += 4;
      }
      for (; p < p1; p += 8) {
        PACC(kA, vA0, vA1, vA2, vA3);
        PLOAD(p, kA, vA0, vA1, vA2, vA3);
        PACC(kB, vB0, vB1, vB2, vB3);
        PLOAD(p + 4, kB, vB0, vB1, vB2, vB3);
      }
      PACC(kA, vA0, vA1, vA2, vA3);
      PACC(kB, vB0, vB1, vB2, vB3);
    }
  }
#undef PLOAD
#undef PACC

  union { ushort8 s; unsigned u[4]; } o;
#pragma unroll
  for (int j = 0; j < 8; j += 2)
    o.u[j >> 1] = f2bf2(a[j], a[j + 1]);
  *(ushort8*)(y + (size_t)c * ldy + d) = o.s;
}

// ---------------- bf16 MFMA GEMM: C = post( sum_c A_c @ B_c ) ----------------
// launch_bounds(256,4): 12 KB LDS -> 4 blocks/CU. XCD-swizzled blockIdx.x (T1).
// Cb path: bf16 ReLU store (layer GEMMs). Fused-logit path (Cb==nullptr): BN epilogue
// then in-register 256x2 matvec -- l15-group shuffle-reduce, 1 atomicAdd pair per
// (row, contributor); removes the 40 MB zbuf round-trip + logit dispatch.
__global__ __launch_bounds__(256, 4) void mgemm_kernel(
    const unsigned short* A0, const unsigned short* A1,
    const unsigned short* A2, const unsigned short* A3,
    int l0, int l1, int l2, int l3, int nchunks,
    const unsigned short* __restrict__ BT, int ldbt,
    unsigned short* __restrict__ Cb, int ldc, int M,
    const float* __restrict__ bias, const float* __restrict__ bng,
    const float* __restrict__ bnb,
    const float* __restrict__ w2p, const float* __restrict__ b2p,
    float* __restrict__ outp)
{
  __shared__ short As[4 * 64 * 8];
  __shared__ short Bs[4 * 128 * 8];
  int tid = threadIdx.x;
  int lane = tid & 63;
  int wv = tid >> 6;
  int l15 = lane & 15, quad = lane >> 4;
  int wr = wv >> 1, wc = wv & 1;
  int bidx = xcd_swizzle(blockIdx.x, gridDim.x);
  int m0 = bidx * 64, n0 = blockIdx.y * 128;

  const unsigned short* Ap[4] = {A0, A1, A2, A3};
  int Al[4] = {l0, l1, l2, l3};

  int arow = tid & 63, ac = tid >> 6;
  int brow = tid & 127, bc = tid >> 7;

  floatx4 acc[2][4];
#pragma unroll
  for (int mi = 0; mi < 2; mi++)
#pragma unroll
    for (int nj = 0; nj < 4; nj++) acc[mi][nj] = (floatx4){0.f, 0.f, 0.f, 0.f};

  for (int c = 0; c < nchunks; c++) {
    const unsigned short* Abase = Ap[c] + (size_t)(m0 + arow) * Al[c] + ac * 8;
    const unsigned short* Bbase = BT + (size_t)(n0 + brow) * ldbt + c * 256 + bc * 8;
#pragma unroll 1
    for (int kb = 0; kb < 256; kb += 32) {
      __syncthreads();
      gl_lds16(Abase + kb, &As[tid * 8]);
      gl_lds16(Bbase + kb, &Bs[tid * 8]);
      gl_lds16(Bbase + 16 + kb, &Bs[(tid + 256) * 8]);
      __syncthreads();
      short8 af[2], bfv[4];
#pragma unroll
      for (int mi = 0; mi < 2; mi++)
        af[mi] = *(const short8*)&As[(quad * 64 + wr * 32 + mi * 16 + l15) * 8];
#pragma unroll
      for (int nj = 0; nj < 4; nj++)
        bfv[nj] = *(const short8*)&Bs[(quad * 128 + wc * 64 + nj * 16 + l15) * 8];
#pragma unroll
      for (int nj = 0; nj < 4; nj++)
#pragma unroll
        for (int mi = 0; mi < 2; mi++)
          acc[mi][nj] = __builtin_amdgcn_mfma_f32_16x16x32_bf16(af[mi], bfv[nj], acc[mi][nj], 0, 0, 0);
    }
  }

  if (Cb) {
#pragma unroll
    for (int mi = 0; mi < 2; mi++)
#pragma unroll
      for (int r = 0; r < 4; r++) {
        int row = m0 + wr * 32 + mi * 16 + quad * 4 + r;
        if (row < M) {
#pragma unroll
          for (int nj = 0; nj < 4; nj++) {
            int col = n0 + wc * 64 + nj * 16 + l15;
            Cb[(size_t)row * ldc + col] = (unsigned short)f2bf(fmaxf(acc[mi][nj][r], 0.f));
          }
        }
      }
  } else {
    float bs[4], g[4], bb[4], wa[4], wb[4];
    bool lead = (n0 == 0) && (wc == 0);   // adds cls bias b2 exactly once per row
#pragma unroll
    for (int nj = 0; nj < 4; nj++) {
      int col = n0 + wc * 64 + nj * 16 + l15;
      bs[nj] = bias[col]; g[nj] = bng[col] * RSBN; bb[nj] = bnb[col];
      wa[nj] = w2p[col * 2]; wb[nj] = w2p[col * 2 + 1];
    }
#pragma unroll
    for (int mi = 0; mi < 2; mi++)
#pragma unroll
      for (int r = 0; r < 4; r++) {
        int row = m0 + wr * 32 + mi * 16 + quad * 4 + r;
        float p0 = 0.f, p1 = 0.f;
#pragma unroll
        for (int nj = 0; nj < 4; nj++) {
          float v = fmaxf(acc[mi][nj][r] + bs[nj], 0.f) * g[nj] + bb[nj];
          p0 += v * wa[nj];
          p1 += v * wb[nj];
        }
#pragma unroll
        for (int m = 1; m < 16; m <<= 1) {   // reduce over l15 (cols) within quad
          p0 += __shfl_xor(p0, m, 64);
          p1 += __shfl_xor(p1, m, 64);
        }
        if (l15 == 0 && row < M) {
          if (lead) { p0 += b2p[0]; p1 += b2p[1]; }
          atomicAdd(&outp[(size_t)row * 2], p0);
          atomicAdd(&outp[(size_t)row * 2 + 1], p1);
        }
      }
  }
}

extern "C" void kernel_launch(void* const* d_in, const int* in_sizes, int n_in,
                              void* d_out, int out_size, void* d_ws, size_t ws_size,
                              hipStream_t stream) {
  const float* features = (const float*)d_in[0];
  const int*   eidx     = (const int*)d_in[1];
  const float* xin      = (const float*)d_in[2];
  const float* cheb_w   = (const float*)d_in[3];
  const float* en_w1    = (const float*)d_in[4];
  const float* en_b1    = (const float*)d_in[5];
  const float* en_g1    = (const float*)d_in[6];
  const float* en_be1   = (const float*)d_in[7];
  const float* en_w2    = (const float*)d_in[8];
  const float* en_b2    = (const float*)d_in[9];
  const float* cls_w1   = (const float*)d_in[10];
  const float* cls_b1   = (const float*)d_in[11];
  const float* cls_g    = (const float*)d_in[12];
  const float* cls_b    = (const float*)d_in[13];
  const float* cls_w2   = (const float*)d_in[14];
  const float* cls_b2   = (const float*)d_in[15];
  float* out = (float*)d_out;

  char* ws = (char*)d_ws;
  size_t off = 0;
  auto alloc = [&](size_t bytes) -> void* {
    void* p = ws + off;
    off += (bytes + 255) & ~(size_t)255;
    return p;
  };
  const int CSRN = EE + 4 * NN;   // padded CSR capacity
  float* deg  = (float*)alloc((size_t)NN * 4);
  int*   cnt  = (int*)  alloc((size_t)NN * 4);
  int*   fil  = (int*)  alloc((size_t)NN * 4);
  int*   hist = (int*)  alloc(64 * 4);
  unsigned* epack = (unsigned*)alloc((size_t)CSRN * 4);
  size_t zero_len = off;                       // deg+cnt+fil+hist+epack zeroed
  int*   ptr  = (int*)  alloc((size_t)(NN + 1) * 4);
  int*   perm = (int*)  alloc((size_t)NN * 4);
  int*   binbase = (int*)alloc(64 * 4);
  int*   binfill = (int*)alloc(64 * 4);
  unsigned short* featb = (unsigned short*)alloc((size_t)NN * 256 * 2);
  unsigned short* Tx1   = (unsigned short*)alloc((size_t)NN * 256 * 2);
  unsigned short* Tx2   = (unsigned short*)alloc((size_t)NN * 256 * 2);
  unsigned short* jk    = (unsigned short*)alloc((size_t)NN * 1024 * 2);
  unsigned short* wtc   = (unsigned short*)alloc((size_t)4 * 196608 * 2);
  unsigned short* clsT  = (unsigned short*)alloc((size_t)256 * 1024 * 2);
  unsigned short* ewf   = (unsigned short*)alloc((size_t)20992 * 2);
  alloc(262144);   // overread pad for GEMM tail blocks

  float* ew = out + (size_t)NN * 2;   // edge-weight output doubles as scratch

  hipMemsetAsync(deg, 0, zero_len, stream);
  hipMemsetAsync(out, 0, (size_t)NN * 2 * 4, stream);   // logit accumulators

  ewconv_kernel<<<1, 256, 0, stream>>>(en_w1, en_w2, en_g1, en_be1, en_b1, en_b2, ewf);
  edge_kernel<<<3125, 512, 0, stream>>>(xin, eidx, ewf, ew, deg, cnt);
  fconv_kernel<<<2500, 256, 0, stream>>>(features, featb);
  wconv_kernel<<<dim3(4, 4, 16), 256, 0, stream>>>(cheb_w, cls_w1, wtc, clsT);
  hist_kernel<<<(NN + 255) / 256, 256, 0, stream>>>(cnt, hist);
  scan_kernel<<<1, 1024, 0, stream>>>(cnt, ptr, hist, binbase, binfill);
  permfill_kernel<<<PB + (EE + 255) / 256, 256, 0, stream>>>(
      cnt, binbase, binfill, perm, eidx, ew, deg, ptr, fil, epack);

  dim3 ggrid(313, 2);
  for (int i = 0; i < 4; i++) {
    const unsigned short* x = (i == 0) ? featb : (jk + (size_t)(i - 1) * 256);
    int ldx = (i == 0) ? 256 : 1024;
    prop_kernel<<<2504, 256, 0, stream>>>(x, ldx, epack, ptr, perm, Tx1, 256);
    prop_kernel<<<2504, 256, 0, stream>>>(Tx1, 256, epack, ptr, perm, Tx2, 256);
    mgemm_kernel<<<ggrid, 256, 0, stream>>>(x, Tx1, Tx2, nullptr, ldx, 256, 256, 0, 3,
                                            wtc + (size_t)i * 196608, 768,
                                            jk + (size_t)i * 256, 1024, NN,
                                            nullptr, nullptr, nullptr,
                                            nullptr, nullptr, nullptr);
  }

  mgemm_kernel<<<ggrid, 256, 0, stream>>>(jk, jk + 256, jk + 512, jk + 768,
                                          1024, 1024, 1024, 1024, 4, clsT, 1024,
                                          nullptr, 0, NN,
                                          cls_b1, cls_g, cls_b,
                                          cls_w2, cls_b2, out);
}